// Round 6
// baseline (1537.501 us; speedup 1.0000x reference)
//
#include <hip/hip_runtime.h>
#include <hip/hip_bf16.h>
#include <stdint.h>
#include <stddef.h>

// Problem constants (fixed by the reference)
#define NN 100000          // nodes
#define NE 3200000         // edges
#define NCAND 1024
#define SCAN_BLOCKS 98     // ceil((NN+1)/1024)
#define NB 391             // buckets of 256 rows: ceil(100000/256)
#define CAP 10240          // bucket capacity (mean 8192, +22 sigma)
#define TILE 8192          // edges per bucketA block

// ---------------- threefry2x32, exact JAX lowering ----------------
__host__ __device__ inline void tf2x32(uint32_t k0, uint32_t k1,
                                       uint32_t x0, uint32_t x1,
                                       uint32_t& y0, uint32_t& y1) {
  uint32_t ks2 = k0 ^ k1 ^ 0x1BD11BDAu;
  x0 += k0; x1 += k1;
#define TFR(r) { x0 += x1; x1 = (x1 << (r)) | (x1 >> (32 - (r))); x1 ^= x0; }
  TFR(13) TFR(15) TFR(26) TFR(6)
  x0 += k1;  x1 += ks2 + 1u;
  TFR(17) TFR(29) TFR(16) TFR(24)
  x0 += ks2; x1 += k0 + 2u;
  TFR(13) TFR(15) TFR(26) TFR(6)
  x0 += k0;  x1 += k1 + 3u;
  TFR(17) TFR(29) TFR(16) TFR(24)
  x0 += k1;  x1 += ks2 + 4u;
  TFR(13) TFR(15) TFR(26) TFR(6)
  x0 += ks2; x1 += k0 + 5u;
#undef TFR
  y0 = x0; y1 = x1;
}

__device__ inline float u01_from_key(uint32_t ka, uint32_t kb, uint32_t idx) {
  uint32_t y0, y1; tf2x32(ka, kb, 0u, idx, y0, y1);
  uint32_t bits = y0 ^ y1;
  return __uint_as_float((bits >> 9) | 0x3F800000u) - 1.0f;
}

// exact numpy pairwise-64 tree via wave shuffles: lane d holds w[d];
// returns the scalar sum (lane0's tree) broadcast to all lanes.
__device__ inline float np_tree64(float w) {
#pragma clang fp contract(off)
  float acc = w;
  acc = acc + __shfl_down(w, 8);
  acc = acc + __shfl_down(w, 16);
  acc = acc + __shfl_down(w, 24);
  acc = acc + __shfl_down(w, 32);
  acc = acc + __shfl_down(w, 40);
  acc = acc + __shfl_down(w, 48);
  acc = acc + __shfl_down(w, 56);
  float u = acc + __shfl_xor(acc, 1);
  float v = u + __shfl_xor(u, 2);
  float f = v + __shfl_xor(v, 4);
  return __shfl(f, 0);
}

// ---------------- phase A: bucket edges by row>>8 with LDS staging ---------
// Writes bbuf[b*CAP + k] = (localrow<<22) | edge_id, coalesced runs per bucket.
__global__ void __launch_bounds__(256) k_bucketA(const int* __restrict__ rows,
                                                 uint32_t* __restrict__ bcur,
                                                 uint32_t* __restrict__ bbuf) {
  __shared__ uint32_t cnt[NB], cnt2[NB], gbase[NB];
  __shared__ uint32_t pref[NB + 1];
  __shared__ uint32_t stage[TILE];
  __shared__ uint16_t stageB[TILE];
  int tid = threadIdx.x;
  int base_e = blockIdx.x * TILE;
  int vcnt = NE - base_e; if (vcnt > TILE) vcnt = TILE;
  for (int j = tid; j < NB; j += 256) { cnt[j] = 0u; cnt2[j] = 0u; }
  __syncthreads();
  for (int i = tid; i < vcnt; i += 256) {
    uint32_t r = (uint32_t)rows[base_e + i];
    atomicAdd(&cnt[r >> 8], 1u);
  }
  __syncthreads();
  if (tid == 0) {
    uint32_t run = 0;
    for (int j = 0; j < NB; j++) { pref[j] = run; run += cnt[j]; }
    pref[NB] = run;
  }
  for (int j = tid; j < NB; j += 256) gbase[j] = atomicAdd(&bcur[j], cnt[j]);
  __syncthreads();
  for (int i = tid; i < vcnt; i += 256) {
    uint32_t e = (uint32_t)(base_e + i);
    uint32_t r = (uint32_t)rows[e];
    uint32_t b = r >> 8, lr = r & 255u;
    uint32_t slot = pref[b] + atomicAdd(&cnt2[b], 1u);
    stage[slot] = (lr << 22) | e;
    stageB[slot] = (uint16_t)b;
  }
  __syncthreads();
  for (int i = tid; i < vcnt; i += 256) {
    uint32_t b = stageB[i];
    uint32_t dst = gbase[b] + ((uint32_t)i - pref[b]);
    bbuf[(size_t)b * CAP + dst] = stage[i];
  }
}

// per-row counts from bucket contents (replaces 3.2M scattered global atomics)
__global__ void __launch_bounds__(256) k_cnt(const uint32_t* __restrict__ bcur,
                                             const uint32_t* __restrict__ bbuf,
                                             uint32_t* __restrict__ total) {
  __shared__ uint32_t cnt[256];
  int b = blockIdx.x, tid = threadIdx.x;
  cnt[tid] = 0u;
  __syncthreads();
  uint32_t nE = bcur[b];
  for (uint32_t i = tid; i < nE; i += 256)
    atomicAdd(&cnt[bbuf[(size_t)b * CAP + i] >> 22], 1u);
  __syncthreads();
  int row = (b << 8) + tid;
  if (row < NN) total[row] = cnt[tid];
}

// ---------------- scan: rstart = exclusive prefix of total ----------------
__global__ void k_scan1(const uint32_t* __restrict__ total, uint32_t* __restrict__ rstart,
                        uint32_t* __restrict__ bsum) {
  __shared__ uint32_t s[1024];
  int i = blockIdx.x * 1024 + threadIdx.x;
  uint32_t v = (i < NN) ? total[i] : 0u;
  s[threadIdx.x] = v; __syncthreads();
  for (int o = 1; o < 1024; o <<= 1) {
    uint32_t x = (threadIdx.x >= (unsigned)o) ? s[threadIdx.x - o] : 0u;
    __syncthreads();
    s[threadIdx.x] += x;
    __syncthreads();
  }
  if (i <= NN) rstart[i] = s[threadIdx.x] - v;
  if (threadIdx.x == 1023) bsum[blockIdx.x] = s[1023];
}

__global__ void k_scan2(uint32_t* __restrict__ bsum) {
  if (blockIdx.x == 0 && threadIdx.x == 0) {
    uint32_t run = 0;
    for (int b = 0; b < SCAN_BLOCKS; b++) { uint32_t t = bsum[b]; bsum[b] = run; run += t; }
  }
}

__global__ void k_scan3(uint32_t* __restrict__ rstart, const uint32_t* __restrict__ bsum) {
  int i = blockIdx.x * 1024 + threadIdx.x;
  if (i <= NN) rstart[i] += bsum[blockIdx.x];
}

// ---------------- phase B: per-bucket CSR build (bin+sort+emit+rowsum) -----
__global__ void __launch_bounds__(256) k_buildB(const uint32_t* __restrict__ bbuf,
    const uint32_t* __restrict__ rstart, const int* __restrict__ cols,
    const float* __restrict__ vals, uint32_t* __restrict__ scol,
    float* __restrict__ v0s, float* __restrict__ vAs, float* __restrict__ vBs,
    float* __restrict__ order0, float* __restrict__ order1,
    uint32_t kd0a, uint32_t kd0b, uint32_t kd1a, uint32_t kd1b) {
#pragma clang fp contract(off)
  __shared__ uint32_t ids[CAP];
  __shared__ uint32_t rbase[257];
  __shared__ uint32_t rcur[256];
  int b = blockIdx.x, tid = threadIdx.x;
  int row0 = b << 8;
  int nrows = NN - row0; if (nrows > 256) nrows = 256;
  uint32_t base = rstart[row0];
  // BUGFIX (round 5 crash): rbase has nrows+1 entries; 256 threads must cover
  // index nrows too (strided loop), else rbase[256] is poison -> nE garbage.
  for (int j = tid; j <= nrows; j += 256) rbase[j] = rstart[row0 + j] - base;
  rcur[tid] = 0u;
  __syncthreads();
  uint32_t nE = rbase[nrows];
  // bin edges into per-row LDS lists (unordered)
  for (uint32_t i = tid; i < nE; i += 256) {
    uint32_t pk = bbuf[(size_t)b * CAP + i];
    uint32_t lr = pk >> 22, e = pk & 0x3FFFFFu;
    uint32_t c = atomicAdd(&rcur[lr], 1u);
    ids[rbase[lr] + c] = e;
  }
  __syncthreads();
  // restore stable (edge-id) order per row
  for (int lr = tid; lr < nrows; lr += 256) {
    uint32_t p0 = rbase[lr], p1 = rbase[lr + 1];
    for (uint32_t i = p0 + 1; i < p1; i++) {
      uint32_t key = ids[i]; uint32_t j = i;
      while (j > p0 && ids[j - 1] > key) { ids[j] = ids[j - 1]; j--; }
      ids[j] = key;
    }
  }
  __syncthreads();
  // emit CSR arrays (coalesced writes; gathers from L3-resident inputs)
  for (uint32_t i = tid; i < nE; i += 256) {
    uint32_t e = ids[i];
    float v = vals[e];
    uint32_t c = (uint32_t)cols[e];
    float m0 = floorf(u01_from_key(kd0a, kd0b, e) + 0.5f);
    float m1 = floorf(u01_from_key(kd1a, kd1b, e) + 0.25f);
    float a = v * m0, b2 = a * m1;
    size_t p = (size_t)base + i;
    scol[p] = c; v0s[p] = v; vAs[p] = a; vBs[p] = b2;
  }
  // rowsum in edge order (recompute mask0; v*m0 is exact, order matches)
  for (int lr = tid; lr < nrows; lr += 256) {
    float o0 = 0.0f, o1 = 0.0f;
    uint32_t p0 = rbase[lr], p1 = rbase[lr + 1];
    for (uint32_t p = p0; p < p1; p++) {
      uint32_t e = ids[p];
      float v = vals[e];
      float m0 = floorf(u01_from_key(kd0a, kd0b, e) + 0.5f);
      o0 = o0 + v;
      o1 = o1 + v * m0;
    }
    order0[row0 + lr] = o0; order1[row0 + lr] = o1;
  }
}

// ---------------- SpMM chain (4 rows per 256-thread block) ----------------
// fst = spmm(vals0, embeds) - embeds
__global__ void __launch_bounds__(256) k_fst(const uint32_t* __restrict__ rp,
    const uint32_t* __restrict__ scol, const float* __restrict__ v0s,
    const float* __restrict__ emb, float* __restrict__ fst) {
#pragma clang fp contract(off)
  int r = blockIdx.x * 4 + (threadIdx.x >> 6);
  if (r >= NN) return;
  int d = threadIdx.x & 63;
  uint32_t p0 = rp[r], p1 = rp[r + 1];
  float acc = 0.0f;
  for (uint32_t p = p0; p < p1; p++) {
    float v = v0s[p]; uint32_t c = scol[p];
    acc = acc + v * emb[(size_t)c * 64 + d];
  }
  fst[(size_t)r * 64 + d] = acc - emb[(size_t)r * 64 + d];
}

// num0 = spmm(vals1, order0) - order0 - order0
__global__ void __launch_bounds__(256) k_numA(const uint32_t* __restrict__ rp,
    const uint32_t* __restrict__ scol, const float* __restrict__ vAs,
    const float* __restrict__ order0, float* __restrict__ num0) {
#pragma clang fp contract(off)
  int r = blockIdx.x * blockDim.x + threadIdx.x;
  if (r >= NN) return;
  uint32_t p0 = rp[r], p1 = rp[r + 1];
  float acc = 0.0f;
  for (uint32_t p = p0; p < p1; p++) acc = acc + vAs[p] * order0[scol[p]];
  float o = order0[r];
  num0[r] = (acc - o) - o;
}

// emb1 = spmm(vals1, fst) - fst - order0*fst
__global__ void __launch_bounds__(256) k_emb1(const uint32_t* __restrict__ rp,
    const uint32_t* __restrict__ scol, const float* __restrict__ vAs,
    const float* __restrict__ fst, const float* __restrict__ order0,
    float* __restrict__ emb1) {
#pragma clang fp contract(off)
  int r = blockIdx.x * 4 + (threadIdx.x >> 6);
  if (r >= NN) return;
  int d = threadIdx.x & 63;
  uint32_t p0 = rp[r], p1 = rp[r + 1];
  float acc = 0.0f;
  for (uint32_t p = p0; p < p1; p++) {
    float v = vAs[p]; uint32_t c = scol[p];
    acc = acc + v * fst[(size_t)c * 64 + d];
  }
  size_t i = (size_t)r * 64 + d;
  float pr = fst[i];
  float t  = order0[r] * pr;
  emb1[i] = (acc - pr) - t;
}

// num_sum = (order0 + num0) + ((spmm(vals2,num0) - num0) - order1)
__global__ void __launch_bounds__(256) k_numB(const uint32_t* __restrict__ rp,
    const uint32_t* __restrict__ scol, const float* __restrict__ vBs,
    const float* __restrict__ num0, const float* __restrict__ order0,
    const float* __restrict__ order1, float* __restrict__ num_sum) {
#pragma clang fp contract(off)
  int r = blockIdx.x * blockDim.x + threadIdx.x;
  if (r >= NN) return;
  uint32_t p0 = rp[r], p1 = rp[r + 1];
  float acc = 0.0f;
  for (uint32_t p = p0; p < p1; p++) acc = acc + vBs[p] * num0[scol[p]];
  float n1 = (acc - num0[r]) - order1[r];
  num_sum[r] = (order0[r] + num0[r]) + n1;
}

// esum = (fst + emb1) + ((spmm(vals2,emb1) - emb1) - order1*emb1); in-place into fst
__global__ void __launch_bounds__(256) k_emb2(const uint32_t* __restrict__ rp,
    const uint32_t* __restrict__ scol, const float* __restrict__ vBs,
    const float* __restrict__ emb1, const float* __restrict__ order1,
    float* __restrict__ fstsum) {
#pragma clang fp contract(off)
  int r = blockIdx.x * 4 + (threadIdx.x >> 6);
  if (r >= NN) return;
  int d = threadIdx.x & 63;
  uint32_t p0 = rp[r], p1 = rp[r + 1];
  float acc = 0.0f;
  for (uint32_t p = p0; p < p1; p++) {
    float v = vBs[p]; uint32_t c = scol[p];
    acc = acc + v * emb1[(size_t)c * 64 + d];
  }
  size_t i = (size_t)r * 64 + d;
  float pr = emb1[i];
  float t  = order1[r] * pr;
  float e2 = (acc - pr) - t;
  fstsum[i] = (fstsum[i] + pr) + e2;
}

// ---------------- scores: one wave per row, exact numpy trees --------------
__global__ void __launch_bounds__(256) k_scores(const float* __restrict__ esum,
    const float* __restrict__ num_sum, const float* __restrict__ emb,
    uint32_t* __restrict__ m_arr, float* __restrict__ out_scores,
    uint32_t kna, uint32_t knb) {
#pragma clang fp contract(off)
  int r = blockIdx.x * 4 + (threadIdx.x >> 6);
  if (r >= NN) return;
  int lane = threadIdx.x & 63;
  size_t ib = (size_t)r * 64 + lane;
  float denom = num_sum[r] + 1e-8f;
  float t = esum[ib] / denom;
  float S1 = np_tree64(t * t);
  float nn = fmaxf(sqrtf(S1), 1e-12f);
  t = t / nn;
  float e = emb[ib];
  float S2 = np_tree64(e * e);
  float mn = fmaxf(sqrtf(S2), 1e-12f);
  float s = np_tree64(t * (e / mn));
  if (lane == 0) {
    float u  = u01_from_key(kna, knb, (uint32_t)r);
    float l1 = (float)log((double)u);
    float l2 = (float)log((double)(-l1));
    s = s + (-l2);
    uint32_t bb = __float_as_uint(s);
    m_arr[r] = bb ^ (uint32_t)(((int32_t)bb >> 31) | (int32_t)0x80000000);
    out_scores[r] = s;
  }
}

// ---------------- exact top-1024: one single-workgroup kernel --------------
__global__ void __launch_bounds__(1024)
k_topk(const uint32_t* __restrict__ m_arr, float* __restrict__ out) {
  __shared__ uint32_t hist[256];
  __shared__ uint32_t selp, need, ccnt;
  __shared__ unsigned long long cbuf[4096];
  int tid = threadIdx.x;
  if (tid == 0) { selp = 0u; need = NCAND; ccnt = 0u; }
  __syncthreads();
  for (int shift = 24; shift >= 0; shift -= 8) {
    if (tid < 256) hist[tid] = 0u;
    __syncthreads();
    uint32_t pref = selp;
    for (int i = tid; i < NN; i += 1024) {
      uint32_t m = m_arr[i];
      bool ok = (shift == 24) || ((m >> (shift + 8)) == pref);
      if (ok) atomicAdd(&hist[(m >> shift) & 255u], 1u);
    }
    __syncthreads();
    if (tid == 0) {
      uint32_t nd = need;
      int b;
      for (b = 255; b > 0; b--) {
        uint32_t c = hist[b];
        if (c < nd) nd -= c; else break;
      }
      selp = (pref << 8) | (uint32_t)b;
      need = nd;
    }
    __syncthreads();
  }
  uint32_t thr = selp;
  for (int i = tid; i < NN; i += 1024) {
    uint32_t m = m_arr[i];
    if (m >= thr) {
      uint32_t pos = atomicAdd(&ccnt, 1u);
      if (pos < 4096u)
        cbuf[pos] = ((unsigned long long)m << 32) | (uint32_t)(~(uint32_t)i);
    }
  }
  __syncthreads();
  uint32_t n = ccnt; if (n > 4096u) n = 4096u;
  for (int i = tid; i < 4096; i += 1024) if (i >= (int)n) cbuf[i] = 0ULL;
  __syncthreads();
  for (int k = 2; k <= 4096; k <<= 1) {
    for (int j = k >> 1; j > 0; j >>= 1) {
      for (int i = tid; i < 4096; i += 1024) {
        int ixj = i ^ j;
        if (ixj > i) {
          bool up = ((i & k) == 0);
          unsigned long long a = cbuf[i], b = cbuf[ixj];
          if ((a > b) == up) { cbuf[i] = b; cbuf[ixj] = a; }
        }
      }
      __syncthreads();
    }
  }
  for (int j = tid; j < NCAND; j += 1024) {
    unsigned long long key = cbuf[4095 - j];
    uint32_t idx = ~(uint32_t)(key & 0xFFFFFFFFull);
    out[j] = (float)idx;
  }
}

// ---------------- launcher ----------------
extern "C" void kernel_launch(void* const* d_in, const int* in_sizes, int n_in,
                              void* d_out, int out_size, void* d_ws, size_t ws_size,
                              hipStream_t stream) {
  (void)in_sizes; (void)n_in; (void)out_size; (void)ws_size;
  const int*   rows = (const int*)d_in[0];
  const int*   cols = (const int*)d_in[1];
  const float* vals = (const float*)d_in[2];
  const float* emb  = (const float*)d_in[3];
  float* out = (float*)d_out;   // f32: scores[NN] then candidates[1024]

  // workspace carve (aligned 256B); total ~120 MB
  char* w = (char*)d_ws;
  auto alloc = [&](size_t bytes) -> void* {
    void* p = (void*)w; w += (bytes + 255) & ~(size_t)255; return p;
  };
  uint32_t* bcur    = (uint32_t*)alloc((size_t)NB * 4);
  uint32_t* bbuf    = (uint32_t*)alloc((size_t)NB * CAP * 4);
  uint32_t* total   = (uint32_t*)alloc((size_t)NN * 4);
  uint32_t* rstart  = (uint32_t*)alloc((size_t)(NN + 1) * 4);
  uint32_t* bsum    = (uint32_t*)alloc((size_t)SCAN_BLOCKS * 4);
  uint32_t* scol    = (uint32_t*)alloc((size_t)NE * 4);
  float*    v0s     = (float*)alloc((size_t)NE * 4);
  float*    vAs     = (float*)alloc((size_t)NE * 4);
  float*    vBs     = (float*)alloc((size_t)NE * 4);
  float*    order0  = (float*)alloc((size_t)NN * 4);
  float*    order1  = (float*)alloc((size_t)NN * 4);
  float*    num0    = (float*)alloc((size_t)NN * 4);
  float*    num_sum = (float*)alloc((size_t)NN * 4);
  float*    fst     = (float*)alloc((size_t)NN * 64 * 4);
  float*    emb1    = (float*)alloc((size_t)NN * 64 * 4);
  uint32_t* m_arr   = (uint32_t*)alloc((size_t)NN * 4);

  // host-side threefry key chain (data-independent):
  // key0=(0,42); key,kd = split(key) twice; key,kn = split(key)
  uint32_t K1a,K1b, kd0a,kd0b, K2a,K2b, kd1a,kd1b, kna,knb;
  tf2x32(0u, 42u, 0u, 0u, K1a, K1b);
  tf2x32(0u, 42u, 0u, 1u, kd0a, kd0b);
  tf2x32(K1a, K1b, 0u, 0u, K2a, K2b);
  tf2x32(K1a, K1b, 0u, 1u, kd1a, kd1b);
  tf2x32(K2a, K2b, 0u, 1u, kna, knb);

  hipMemsetAsync(bcur, 0, (size_t)NB * 4, stream);

  const int TPB = 256;
  k_bucketA<<<(NE + TILE - 1) / TILE, TPB, 0, stream>>>(rows, bcur, bbuf);
  k_cnt<<<NB, TPB, 0, stream>>>(bcur, bbuf, total);
  k_scan1<<<SCAN_BLOCKS, 1024, 0, stream>>>(total, rstart, bsum);
  k_scan2<<<1, 1, 0, stream>>>(bsum);
  k_scan3<<<SCAN_BLOCKS, 1024, 0, stream>>>(rstart, bsum);
  k_buildB<<<NB, TPB, 0, stream>>>(bbuf, rstart, cols, vals, scol, v0s, vAs, vBs,
                                   order0, order1, kd0a, kd0b, kd1a, kd1b);
  k_fst<<<(NN + 3) / 4, TPB, 0, stream>>>(rstart, scol, v0s, emb, fst);
  k_numA<<<(NN + TPB - 1) / TPB, TPB, 0, stream>>>(rstart, scol, vAs, order0, num0);
  k_emb1<<<(NN + 3) / 4, TPB, 0, stream>>>(rstart, scol, vAs, fst, order0, emb1);
  k_numB<<<(NN + TPB - 1) / TPB, TPB, 0, stream>>>(rstart, scol, vBs, num0, order0, order1, num_sum);
  k_emb2<<<(NN + 3) / 4, TPB, 0, stream>>>(rstart, scol, vBs, emb1, order1, fst);
  k_scores<<<(NN + 3) / 4, TPB, 0, stream>>>(fst, num_sum, emb, m_arr, out, kna, knb);
  k_topk<<<1, 1024, 0, stream>>>(m_arr, out + NN);
}

// Round 7
// 833.485 us; speedup vs baseline: 1.8447x; 1.8447x over previous
//
#include <hip/hip_runtime.h>
#include <hip/hip_bf16.h>
#include <stdint.h>
#include <stddef.h>

// Problem constants (fixed by the reference)
#define NN 100000          // nodes
#define NE 3200000         // edges
#define NCAND 1024
#define SCAN_BLOCKS 98     // ceil((NN+1)/1024)
#define NB 391             // buckets of 256 rows: ceil(100000/256)
#define CAP 10240          // bucket capacity (mean 8184, +22 sigma)
#define TILE 4096          // edges per bucketA block (LDS: 3 staged words)
#define NA_CAP 1700000     // level-1 compact bound (mean 1.6M, +100 sigma)
#define NB_CAP 500000      // level-2 compact bound (mean 400k, +84 sigma)

// ---------------- threefry2x32, exact JAX lowering ----------------
__host__ __device__ inline void tf2x32(uint32_t k0, uint32_t k1,
                                       uint32_t x0, uint32_t x1,
                                       uint32_t& y0, uint32_t& y1) {
  uint32_t ks2 = k0 ^ k1 ^ 0x1BD11BDAu;
  x0 += k0; x1 += k1;
#define TFR(r) { x0 += x1; x1 = (x1 << (r)) | (x1 >> (32 - (r))); x1 ^= x0; }
  TFR(13) TFR(15) TFR(26) TFR(6)
  x0 += k1;  x1 += ks2 + 1u;
  TFR(17) TFR(29) TFR(16) TFR(24)
  x0 += ks2; x1 += k0 + 2u;
  TFR(13) TFR(15) TFR(26) TFR(6)
  x0 += k0;  x1 += k1 + 3u;
  TFR(17) TFR(29) TFR(16) TFR(24)
  x0 += k1;  x1 += ks2 + 4u;
  TFR(13) TFR(15) TFR(26) TFR(6)
  x0 += ks2; x1 += k0 + 5u;
#undef TFR
  y0 = x0; y1 = x1;
}

__device__ inline float u01_from_key(uint32_t ka, uint32_t kb, uint32_t idx) {
  uint32_t y0, y1; tf2x32(ka, kb, 0u, idx, y0, y1);
  uint32_t bits = y0 ^ y1;
  return __uint_as_float((bits >> 9) | 0x3F800000u) - 1.0f;
}

// exact numpy pairwise-64 tree via wave shuffles
__device__ inline float np_tree64(float w) {
#pragma clang fp contract(off)
  float acc = w;
  acc = acc + __shfl_down(w, 8);
  acc = acc + __shfl_down(w, 16);
  acc = acc + __shfl_down(w, 24);
  acc = acc + __shfl_down(w, 32);
  acc = acc + __shfl_down(w, 40);
  acc = acc + __shfl_down(w, 48);
  acc = acc + __shfl_down(w, 56);
  float u = acc + __shfl_xor(acc, 1);
  float v = u + __shfl_xor(u, 2);
  float f = v + __shfl_xor(v, 4);
  return __shfl(f, 0);
}

// ---------------- phase A: bucket edges by row>>8, carrying col/val --------
// bbufE[b*CAP+k] = (bothmask<<31)|(m0<<30)|(lr<<22)|e ; bbufC/bbufV parallel.
__global__ void __launch_bounds__(256) k_bucketA(const int* __restrict__ rows,
    const int* __restrict__ cols, const float* __restrict__ vals,
    uint32_t* __restrict__ bcur, uint32_t* __restrict__ bbufE,
    uint32_t* __restrict__ bbufC, float* __restrict__ bbufV,
    uint32_t kd0a, uint32_t kd0b, uint32_t kd1a, uint32_t kd1b) {
  __shared__ uint32_t cnt[NB], cnt2[NB], gbase[NB];
  __shared__ uint32_t pref[NB + 1];
  __shared__ uint32_t stageE[TILE];
  __shared__ uint32_t stageC[TILE];
  __shared__ float    stageV[TILE];
  __shared__ uint16_t stageB[TILE];
  int tid = threadIdx.x;
  int base_e = blockIdx.x * TILE;
  int vcnt = NE - base_e; if (vcnt > TILE) vcnt = TILE;
  for (int j = tid; j < NB; j += 256) { cnt[j] = 0u; cnt2[j] = 0u; }
  __syncthreads();
  for (int i = tid; i < vcnt; i += 256) {
    uint32_t r = (uint32_t)rows[base_e + i];
    atomicAdd(&cnt[r >> 8], 1u);
  }
  __syncthreads();
  if (tid == 0) {
    uint32_t run = 0;
    for (int j = 0; j < NB; j++) { pref[j] = run; run += cnt[j]; }
    pref[NB] = run;
  }
  for (int j = tid; j < NB; j += 256) gbase[j] = atomicAdd(&bcur[j], cnt[j]);
  __syncthreads();
  for (int i = tid; i < vcnt; i += 256) {
    uint32_t e = (uint32_t)(base_e + i);
    uint32_t r = (uint32_t)rows[e];
    uint32_t b = r >> 8, lr = r & 255u;
    uint32_t m0 = (u01_from_key(kd0a, kd0b, e) >= 0.5f) ? 1u : 0u;
    uint32_t m1 = (u01_from_key(kd1a, kd1b, e) >= 0.75f) ? 1u : 0u;
    uint32_t flags = (m0 << 30) | ((m0 & m1) << 31);
    uint32_t slot = pref[b] + atomicAdd(&cnt2[b], 1u);
    stageE[slot] = flags | (lr << 22) | e;
    stageC[slot] = (uint32_t)cols[e];
    stageV[slot] = vals[e];
    stageB[slot] = (uint16_t)b;
  }
  __syncthreads();
  for (int i = tid; i < vcnt; i += 256) {
    uint32_t b = stageB[i];
    size_t dst = (size_t)b * CAP + gbase[b] + ((uint32_t)i - pref[b]);
    bbufE[dst] = stageE[i];
    bbufC[dst] = stageC[i];
    bbufV[dst] = stageV[i];
  }
}

// per-row counts (full / level-1 / level-2) from packed flags
__global__ void __launch_bounds__(256) k_cnt(const uint32_t* __restrict__ bcur,
    const uint32_t* __restrict__ bbufE, uint32_t* __restrict__ total,
    uint32_t* __restrict__ totalA, uint32_t* __restrict__ totalB) {
  __shared__ uint32_t c0[256], c1[256], c2[256];
  int b = blockIdx.x, tid = threadIdx.x;
  c0[tid] = 0u; c1[tid] = 0u; c2[tid] = 0u;
  __syncthreads();
  uint32_t nE = bcur[b];
  for (uint32_t i = tid; i < nE; i += 256) {
    uint32_t pk = bbufE[(size_t)b * CAP + i];
    uint32_t lr = (pk >> 22) & 255u;
    atomicAdd(&c0[lr], 1u);
    if (pk & 0x40000000u) atomicAdd(&c1[lr], 1u);
    if (pk & 0x80000000u) atomicAdd(&c2[lr], 1u);
  }
  __syncthreads();
  int row = (b << 8) + tid;
  if (row < NN) { total[row] = c0[tid]; totalA[row] = c1[tid]; totalB[row] = c2[tid]; }
}

// ---------------- scan (generic): rstart = exclusive prefix ----------------
__global__ void k_scan1(const uint32_t* __restrict__ total, uint32_t* __restrict__ rstart,
                        uint32_t* __restrict__ bsum) {
  __shared__ uint32_t s[1024];
  int i = blockIdx.x * 1024 + threadIdx.x;
  uint32_t v = (i < NN) ? total[i] : 0u;
  s[threadIdx.x] = v; __syncthreads();
  for (int o = 1; o < 1024; o <<= 1) {
    uint32_t x = (threadIdx.x >= (unsigned)o) ? s[threadIdx.x - o] : 0u;
    __syncthreads();
    s[threadIdx.x] += x;
    __syncthreads();
  }
  if (i <= NN) rstart[i] = s[threadIdx.x] - v;
  if (threadIdx.x == 1023) bsum[blockIdx.x] = s[1023];
}

__global__ void k_scan2(uint32_t* __restrict__ bsum) {
  if (blockIdx.x == 0 && threadIdx.x == 0) {
    uint32_t run = 0;
    for (int b = 0; b < SCAN_BLOCKS; b++) { uint32_t t = bsum[b]; bsum[b] = run; run += t; }
  }
}

__global__ void k_scan3(uint32_t* __restrict__ rstart, const uint32_t* __restrict__ bsum) {
  int i = blockIdx.x * 1024 + threadIdx.x;
  if (i <= NN) rstart[i] += bsum[blockIdx.x];
}

// ---------------- phase B: per-bucket stable CSR build + compaction --------
__global__ void __launch_bounds__(256) k_buildB(const uint32_t* __restrict__ bbufE,
    const uint32_t* __restrict__ bbufC, const float* __restrict__ bbufV,
    const uint32_t* __restrict__ rstart, const uint32_t* __restrict__ rstartA,
    const uint32_t* __restrict__ rstartB,
    uint32_t* __restrict__ scol, float* __restrict__ v0s,
    uint32_t* __restrict__ scolA, float* __restrict__ vAa,
    uint32_t* __restrict__ scolB, float* __restrict__ vBa,
    float* __restrict__ order0, float* __restrict__ order1) {
#pragma clang fp contract(off)
  __shared__ uint32_t eidp[CAP];
  __shared__ uint16_t slot[CAP];
  __shared__ uint32_t rbase[257];
  __shared__ uint32_t rcur[256];
  int b = blockIdx.x, tid = threadIdx.x;
  int row0 = b << 8;
  int nrows = NN - row0; if (nrows > 256) nrows = 256;
  uint32_t base = rstart[row0];
  for (int j = tid; j <= nrows; j += 256) rbase[j] = rstart[row0 + j] - base;
  rcur[tid] = 0u;
  __syncthreads();
  uint32_t nE = rbase[nrows];
  const uint32_t* bE = bbufE + (size_t)b * CAP;
  const uint32_t* bC = bbufC + (size_t)b * CAP;
  const float*    bV = bbufV + (size_t)b * CAP;
  // bin into per-row LDS lists (unordered)
  for (uint32_t i = tid; i < nE; i += 256) {
    uint32_t pk = bE[i];
    uint32_t lr = (pk >> 22) & 255u;
    uint32_t c = atomicAdd(&rcur[lr], 1u);
    uint32_t pos = rbase[lr] + c;
    eidp[pos] = pk;
    slot[pos] = (uint16_t)i;
  }
  __syncthreads();
  // restore stable (edge-id) order per row; mirror slot moves
  for (int lr = tid; lr < nrows; lr += 256) {
    uint32_t p0 = rbase[lr], p1 = rbase[lr + 1];
    for (uint32_t i = p0 + 1; i < p1; i++) {
      uint32_t key = eidp[i]; uint16_t ks = slot[i];
      uint32_t ke = key & 0x3FFFFFu;
      uint32_t j = i;
      while (j > p0 && (eidp[j - 1] & 0x3FFFFFu) > ke) {
        eidp[j] = eidp[j - 1]; slot[j] = slot[j - 1]; j--;
      }
      eidp[j] = key; slot[j] = ks;
    }
  }
  __syncthreads();
  // emit full arrays (coalesced writes; bC/bV slot reads are L1-local)
  for (uint32_t i = tid; i < nE; i += 256) {
    uint32_t s = slot[i];
    scol[(size_t)base + i] = bC[s];
    v0s[(size_t)base + i] = bV[s];
  }
  // per-row pass: compacted emits + rowsums in edge order (bit-identical:
  // skipped terms are exact +/-0 contributions)
  for (int lr = tid; lr < nrows; lr += 256) {
    uint32_t p0 = rbase[lr], p1 = rbase[lr + 1];
    uint32_t wA = rstartA[row0 + lr];
    uint32_t wB = rstartB[row0 + lr];
    float o0 = 0.0f, o1 = 0.0f;
    for (uint32_t p = p0; p < p1; p++) {
      uint32_t pk = eidp[p];
      uint32_t s = slot[p];
      float v = bV[s];
      o0 = o0 + v;
      if (pk & 0x40000000u) {
        o1 = o1 + v;
        uint32_t c = bC[s];
        scolA[wA] = c; vAa[wA] = v; wA++;
        if (pk & 0x80000000u) { scolB[wB] = c; vBa[wB] = v; wB++; }
      }
    }
    order0[row0 + lr] = o0; order1[row0 + lr] = o1;
  }
}

// ---------------- SpMM chain (wave per row, unroll-4 for MLP) --------------
// fst = spmm(vals0, embeds) - embeds
__global__ void __launch_bounds__(256) k_fst(const uint32_t* __restrict__ rp,
    const uint32_t* __restrict__ scol, const float* __restrict__ v0s,
    const float* __restrict__ emb, float* __restrict__ fst) {
#pragma clang fp contract(off)
  int r = blockIdx.x * 4 + (threadIdx.x >> 6);
  if (r >= NN) return;
  int d = threadIdx.x & 63;
  uint32_t p0 = rp[r], p1 = rp[r + 1];
  float acc = 0.0f;
  uint32_t p = p0;
  for (; p + 4 <= p1; p += 4) {
    uint32_t c0 = scol[p], c1 = scol[p + 1], c2 = scol[p + 2], c3 = scol[p + 3];
    float v0 = v0s[p], v1 = v0s[p + 1], v2 = v0s[p + 2], v3 = v0s[p + 3];
    float e0 = emb[(size_t)c0 * 64 + d];
    float e1 = emb[(size_t)c1 * 64 + d];
    float e2 = emb[(size_t)c2 * 64 + d];
    float e3 = emb[(size_t)c3 * 64 + d];
    acc = acc + v0 * e0; acc = acc + v1 * e1;
    acc = acc + v2 * e2; acc = acc + v3 * e3;
  }
  for (; p < p1; p++) acc = acc + v0s[p] * emb[(size_t)scol[p] * 64 + d];
  fst[(size_t)r * 64 + d] = acc - emb[(size_t)r * 64 + d];
}

// num0 = spmm(vals1, order0) - order0 - order0   (compact level-1 lists)
__global__ void __launch_bounds__(256) k_numA(const uint32_t* __restrict__ rpA,
    const uint32_t* __restrict__ scolA, const float* __restrict__ vAa,
    const float* __restrict__ order0, float* __restrict__ num0) {
#pragma clang fp contract(off)
  int r = blockIdx.x * blockDim.x + threadIdx.x;
  if (r >= NN) return;
  uint32_t p0 = rpA[r], p1 = rpA[r + 1];
  float acc = 0.0f;
  uint32_t p = p0;
  for (; p + 4 <= p1; p += 4) {
    uint32_t c0 = scolA[p], c1 = scolA[p + 1], c2 = scolA[p + 2], c3 = scolA[p + 3];
    float v0 = vAa[p], v1 = vAa[p + 1], v2 = vAa[p + 2], v3 = vAa[p + 3];
    float o0 = order0[c0], o1 = order0[c1], o2 = order0[c2], o3 = order0[c3];
    acc = acc + v0 * o0; acc = acc + v1 * o1;
    acc = acc + v2 * o2; acc = acc + v3 * o3;
  }
  for (; p < p1; p++) acc = acc + vAa[p] * order0[scolA[p]];
  float o = order0[r];
  num0[r] = (acc - o) - o;
}

// emb1 = spmm(vals1, fst) - fst - order0*fst     (compact level-1 lists)
__global__ void __launch_bounds__(256) k_emb1(const uint32_t* __restrict__ rpA,
    const uint32_t* __restrict__ scolA, const float* __restrict__ vAa,
    const float* __restrict__ fst, const float* __restrict__ order0,
    float* __restrict__ emb1) {
#pragma clang fp contract(off)
  int r = blockIdx.x * 4 + (threadIdx.x >> 6);
  if (r >= NN) return;
  int d = threadIdx.x & 63;
  uint32_t p0 = rpA[r], p1 = rpA[r + 1];
  float acc = 0.0f;
  uint32_t p = p0;
  for (; p + 4 <= p1; p += 4) {
    uint32_t c0 = scolA[p], c1 = scolA[p + 1], c2 = scolA[p + 2], c3 = scolA[p + 3];
    float v0 = vAa[p], v1 = vAa[p + 1], v2 = vAa[p + 2], v3 = vAa[p + 3];
    float e0 = fst[(size_t)c0 * 64 + d];
    float e1 = fst[(size_t)c1 * 64 + d];
    float e2 = fst[(size_t)c2 * 64 + d];
    float e3 = fst[(size_t)c3 * 64 + d];
    acc = acc + v0 * e0; acc = acc + v1 * e1;
    acc = acc + v2 * e2; acc = acc + v3 * e3;
  }
  for (; p < p1; p++) acc = acc + vAa[p] * fst[(size_t)scolA[p] * 64 + d];
  size_t i = (size_t)r * 64 + d;
  float pr = fst[i];
  float t  = order0[r] * pr;
  emb1[i] = (acc - pr) - t;
}

// num_sum = (order0 + num0) + ((spmm(vals2,num0) - num0) - order1)
__global__ void __launch_bounds__(256) k_numB(const uint32_t* __restrict__ rpB,
    const uint32_t* __restrict__ scolB, const float* __restrict__ vBa,
    const float* __restrict__ num0, const float* __restrict__ order0,
    const float* __restrict__ order1, float* __restrict__ num_sum) {
#pragma clang fp contract(off)
  int r = blockIdx.x * blockDim.x + threadIdx.x;
  if (r >= NN) return;
  uint32_t p0 = rpB[r], p1 = rpB[r + 1];
  float acc = 0.0f;
  for (uint32_t p = p0; p < p1; p++) acc = acc + vBa[p] * num0[scolB[p]];
  float n1 = (acc - num0[r]) - order1[r];
  num_sum[r] = (order0[r] + num0[r]) + n1;
}

// esum = (fst + emb1) + ((spmm(vals2,emb1) - emb1) - order1*emb1); into fst
__global__ void __launch_bounds__(256) k_emb2(const uint32_t* __restrict__ rpB,
    const uint32_t* __restrict__ scolB, const float* __restrict__ vBa,
    const float* __restrict__ emb1, const float* __restrict__ order1,
    float* __restrict__ fstsum) {
#pragma clang fp contract(off)
  int r = blockIdx.x * 4 + (threadIdx.x >> 6);
  if (r >= NN) return;
  int d = threadIdx.x & 63;
  uint32_t p0 = rpB[r], p1 = rpB[r + 1];
  float acc = 0.0f;
  uint32_t p = p0;
  for (; p + 4 <= p1; p += 4) {
    uint32_t c0 = scolB[p], c1 = scolB[p + 1], c2 = scolB[p + 2], c3 = scolB[p + 3];
    float v0 = vBa[p], v1 = vBa[p + 1], v2 = vBa[p + 2], v3 = vBa[p + 3];
    float e0 = emb1[(size_t)c0 * 64 + d];
    float e1 = emb1[(size_t)c1 * 64 + d];
    float e2 = emb1[(size_t)c2 * 64 + d];
    float e3 = emb1[(size_t)c3 * 64 + d];
    acc = acc + v0 * e0; acc = acc + v1 * e1;
    acc = acc + v2 * e2; acc = acc + v3 * e3;
  }
  for (; p < p1; p++) acc = acc + vBa[p] * emb1[(size_t)scolB[p] * 64 + d];
  size_t i = (size_t)r * 64 + d;
  float pr = emb1[i];
  float t  = order1[r] * pr;
  float e2v = (acc - pr) - t;
  fstsum[i] = (fstsum[i] + pr) + e2v;
}

// ---------------- scores: one wave per row, exact numpy trees --------------
__global__ void __launch_bounds__(256) k_scores(const float* __restrict__ esum,
    const float* __restrict__ num_sum, const float* __restrict__ emb,
    uint32_t* __restrict__ m_arr, float* __restrict__ out_scores,
    uint32_t kna, uint32_t knb) {
#pragma clang fp contract(off)
  int r = blockIdx.x * 4 + (threadIdx.x >> 6);
  if (r >= NN) return;
  int lane = threadIdx.x & 63;
  size_t ib = (size_t)r * 64 + lane;
  float denom = num_sum[r] + 1e-8f;
  float t = esum[ib] / denom;
  float S1 = np_tree64(t * t);
  float nn = fmaxf(sqrtf(S1), 1e-12f);
  t = t / nn;
  float e = emb[ib];
  float S2 = np_tree64(e * e);
  float mn = fmaxf(sqrtf(S2), 1e-12f);
  float s = np_tree64(t * (e / mn));
  if (lane == 0) {
    float u  = u01_from_key(kna, knb, (uint32_t)r);
    float l1 = (float)log((double)u);
    float l2 = (float)log((double)(-l1));
    s = s + (-l2);
    uint32_t bb = __float_as_uint(s);
    m_arr[r] = bb ^ (uint32_t)(((int32_t)bb >> 31) | (int32_t)0x80000000);
    out_scores[r] = s;
  }
}

// ---------------- exact top-1024: one single-workgroup kernel --------------
__global__ void __launch_bounds__(1024)
k_topk(const uint32_t* __restrict__ m_arr, float* __restrict__ out) {
  __shared__ uint32_t hist[256];
  __shared__ uint32_t selp, need, ccnt;
  __shared__ unsigned long long cbuf[4096];
  int tid = threadIdx.x;
  if (tid == 0) { selp = 0u; need = NCAND; ccnt = 0u; }
  __syncthreads();
  for (int shift = 24; shift >= 0; shift -= 8) {
    if (tid < 256) hist[tid] = 0u;
    __syncthreads();
    uint32_t pref = selp;
    for (int i = tid; i < NN; i += 1024) {
      uint32_t m = m_arr[i];
      bool ok = (shift == 24) || ((m >> (shift + 8)) == pref);
      if (ok) atomicAdd(&hist[(m >> shift) & 255u], 1u);
    }
    __syncthreads();
    if (tid == 0) {
      uint32_t nd = need;
      int b;
      for (b = 255; b > 0; b--) {
        uint32_t c = hist[b];
        if (c < nd) nd -= c; else break;
      }
      selp = (pref << 8) | (uint32_t)b;
      need = nd;
    }
    __syncthreads();
  }
  uint32_t thr = selp;
  for (int i = tid; i < NN; i += 1024) {
    uint32_t m = m_arr[i];
    if (m >= thr) {
      uint32_t pos = atomicAdd(&ccnt, 1u);
      if (pos < 4096u)
        cbuf[pos] = ((unsigned long long)m << 32) | (uint32_t)(~(uint32_t)i);
    }
  }
  __syncthreads();
  uint32_t n = ccnt; if (n > 4096u) n = 4096u;
  for (int i = tid; i < 4096; i += 1024) if (i >= (int)n) cbuf[i] = 0ULL;
  __syncthreads();
  for (int k = 2; k <= 4096; k <<= 1) {
    for (int j = k >> 1; j > 0; j >>= 1) {
      for (int i = tid; i < 4096; i += 1024) {
        int ixj = i ^ j;
        if (ixj > i) {
          bool up = ((i & k) == 0);
          unsigned long long a = cbuf[i], b = cbuf[ixj];
          if ((a > b) == up) { cbuf[i] = b; cbuf[ixj] = a; }
        }
      }
      __syncthreads();
    }
  }
  for (int j = tid; j < NCAND; j += 1024) {
    unsigned long long key = cbuf[4095 - j];
    uint32_t idx = ~(uint32_t)(key & 0xFFFFFFFFull);
    out[j] = (float)idx;
  }
}

// ---------------- launcher ----------------
extern "C" void kernel_launch(void* const* d_in, const int* in_sizes, int n_in,
                              void* d_out, int out_size, void* d_ws, size_t ws_size,
                              hipStream_t stream) {
  (void)in_sizes; (void)n_in; (void)out_size; (void)ws_size;
  const int*   rows = (const int*)d_in[0];
  const int*   cols = (const int*)d_in[1];
  const float* vals = (const float*)d_in[2];
  const float* emb  = (const float*)d_in[3];
  float* out = (float*)d_out;   // f32: scores[NN] then candidates[1024]

  char* w = (char*)d_ws;
  auto alloc = [&](size_t bytes) -> void* {
    void* p = (void*)w; w += (bytes + 255) & ~(size_t)255; return p;
  };
  uint32_t* bcur    = (uint32_t*)alloc((size_t)NB * 4);
  uint32_t* bbufE   = (uint32_t*)alloc((size_t)NB * CAP * 4);
  uint32_t* bbufC   = (uint32_t*)alloc((size_t)NB * CAP * 4);
  float*    bbufV   = (float*)   alloc((size_t)NB * CAP * 4);
  uint32_t* total   = (uint32_t*)alloc((size_t)NN * 4);
  uint32_t* totalA  = (uint32_t*)alloc((size_t)NN * 4);
  uint32_t* totalB  = (uint32_t*)alloc((size_t)NN * 4);
  uint32_t* rstart  = (uint32_t*)alloc((size_t)(NN + 1) * 4);
  uint32_t* rstartA = (uint32_t*)alloc((size_t)(NN + 1) * 4);
  uint32_t* rstartB = (uint32_t*)alloc((size_t)(NN + 1) * 4);
  uint32_t* bsum    = (uint32_t*)alloc((size_t)SCAN_BLOCKS * 4);
  uint32_t* scol    = (uint32_t*)alloc((size_t)NE * 4);
  float*    v0s     = (float*)   alloc((size_t)NE * 4);
  uint32_t* scolA   = (uint32_t*)alloc((size_t)NA_CAP * 4);
  float*    vAa     = (float*)   alloc((size_t)NA_CAP * 4);
  uint32_t* scolB   = (uint32_t*)alloc((size_t)NB_CAP * 4);
  float*    vBa     = (float*)   alloc((size_t)NB_CAP * 4);
  float*    order0  = (float*)   alloc((size_t)NN * 4);
  float*    order1  = (float*)   alloc((size_t)NN * 4);
  float*    num0    = (float*)   alloc((size_t)NN * 4);
  float*    num_sum = (float*)   alloc((size_t)NN * 4);
  float*    fst     = (float*)   alloc((size_t)NN * 64 * 4);
  float*    emb1    = (float*)   alloc((size_t)NN * 64 * 4);
  uint32_t* m_arr   = (uint32_t*)alloc((size_t)NN * 4);

  // host-side threefry key chain (data-independent)
  uint32_t K1a,K1b, kd0a,kd0b, K2a,K2b, kd1a,kd1b, kna,knb;
  tf2x32(0u, 42u, 0u, 0u, K1a, K1b);
  tf2x32(0u, 42u, 0u, 1u, kd0a, kd0b);
  tf2x32(K1a, K1b, 0u, 0u, K2a, K2b);
  tf2x32(K1a, K1b, 0u, 1u, kd1a, kd1b);
  tf2x32(K2a, K2b, 0u, 1u, kna, knb);

  hipMemsetAsync(bcur, 0, (size_t)NB * 4, stream);

  const int TPB = 256;
  k_bucketA<<<(NE + TILE - 1) / TILE, TPB, 0, stream>>>(rows, cols, vals, bcur,
      bbufE, bbufC, bbufV, kd0a, kd0b, kd1a, kd1b);
  k_cnt<<<NB, TPB, 0, stream>>>(bcur, bbufE, total, totalA, totalB);
  k_scan1<<<SCAN_BLOCKS, 1024, 0, stream>>>(total, rstart, bsum);
  k_scan2<<<1, 1, 0, stream>>>(bsum);
  k_scan3<<<SCAN_BLOCKS, 1024, 0, stream>>>(rstart, bsum);
  k_scan1<<<SCAN_BLOCKS, 1024, 0, stream>>>(totalA, rstartA, bsum);
  k_scan2<<<1, 1, 0, stream>>>(bsum);
  k_scan3<<<SCAN_BLOCKS, 1024, 0, stream>>>(rstartA, bsum);
  k_scan1<<<SCAN_BLOCKS, 1024, 0, stream>>>(totalB, rstartB, bsum);
  k_scan2<<<1, 1, 0, stream>>>(bsum);
  k_scan3<<<SCAN_BLOCKS, 1024, 0, stream>>>(rstartB, bsum);
  k_buildB<<<NB, TPB, 0, stream>>>(bbufE, bbufC, bbufV, rstart, rstartA, rstartB,
      scol, v0s, scolA, vAa, scolB, vBa, order0, order1);
  k_fst<<<(NN + 3) / 4, TPB, 0, stream>>>(rstart, scol, v0s, emb, fst);
  k_numA<<<(NN + TPB - 1) / TPB, TPB, 0, stream>>>(rstartA, scolA, vAa, order0, num0);
  k_emb1<<<(NN + 3) / 4, TPB, 0, stream>>>(rstartA, scolA, vAa, fst, order0, emb1);
  k_numB<<<(NN + TPB - 1) / TPB, TPB, 0, stream>>>(rstartB, scolB, vBa, num0, order0, order1, num_sum);
  k_emb2<<<(NN + 3) / 4, TPB, 0, stream>>>(rstartB, scolB, vBa, emb1, order1, fst);
  k_scores<<<(NN + 3) / 4, TPB, 0, stream>>>(fst, num_sum, emb, m_arr, out, kna, knb);
  k_topk<<<1, 1024, 0, stream>>>(m_arr, out + NN);
}

// Round 8
// 810.976 us; speedup vs baseline: 1.8959x; 1.0278x over previous
//
#include <hip/hip_runtime.h>
#include <hip/hip_bf16.h>
#include <stdint.h>
#include <stddef.h>

// Problem constants (fixed by the reference)
#define NN 100000          // nodes
#define NE 3200000         // edges
#define NCAND 1024
#define SCAN_BLOCKS 98     // ceil((NN+1)/1024)
#define NB 391             // buckets of 256 rows: ceil(100000/256)
#define CAP 10240          // bucket capacity (mean 8184, +22 sigma)
#define TILE 4096          // edges per bucketA block (LDS: 3 staged words)
#define NA_CAP 1700000     // level-1 compact bound (mean 1.6M, +100 sigma)
#define NB_CAP 500000      // level-2 compact bound (mean 400k, +84 sigma)
#define HBINS 65536

// ---------------- threefry2x32, exact JAX lowering ----------------
__host__ __device__ inline void tf2x32(uint32_t k0, uint32_t k1,
                                       uint32_t x0, uint32_t x1,
                                       uint32_t& y0, uint32_t& y1) {
  uint32_t ks2 = k0 ^ k1 ^ 0x1BD11BDAu;
  x0 += k0; x1 += k1;
#define TFR(r) { x0 += x1; x1 = (x1 << (r)) | (x1 >> (32 - (r))); x1 ^= x0; }
  TFR(13) TFR(15) TFR(26) TFR(6)
  x0 += k1;  x1 += ks2 + 1u;
  TFR(17) TFR(29) TFR(16) TFR(24)
  x0 += ks2; x1 += k0 + 2u;
  TFR(13) TFR(15) TFR(26) TFR(6)
  x0 += k0;  x1 += k1 + 3u;
  TFR(17) TFR(29) TFR(16) TFR(24)
  x0 += k1;  x1 += ks2 + 4u;
  TFR(13) TFR(15) TFR(26) TFR(6)
  x0 += ks2; x1 += k0 + 5u;
#undef TFR
  y0 = x0; y1 = x1;
}

__device__ inline float u01_from_key(uint32_t ka, uint32_t kb, uint32_t idx) {
  uint32_t y0, y1; tf2x32(ka, kb, 0u, idx, y0, y1);
  uint32_t bits = y0 ^ y1;
  return __uint_as_float((bits >> 9) | 0x3F800000u) - 1.0f;
}

// exact numpy pairwise-64 tree via wave shuffles
__device__ inline float np_tree64(float w) {
#pragma clang fp contract(off)
  float acc = w;
  acc = acc + __shfl_down(w, 8);
  acc = acc + __shfl_down(w, 16);
  acc = acc + __shfl_down(w, 24);
  acc = acc + __shfl_down(w, 32);
  acc = acc + __shfl_down(w, 40);
  acc = acc + __shfl_down(w, 48);
  acc = acc + __shfl_down(w, 56);
  float u = acc + __shfl_xor(acc, 1);
  float v = u + __shfl_xor(u, 2);
  float f = v + __shfl_xor(v, 4);
  return __shfl(f, 0);
}

// ---------------- phase A: bucket edges by row>>8, carrying col/val --------
// bbufE[b*CAP+k] = (bothmask<<31)|(m0<<30)|(lr<<22)|e ; bbufC/bbufV parallel.
__global__ void __launch_bounds__(256) k_bucketA(const int* __restrict__ rows,
    const int* __restrict__ cols, const float* __restrict__ vals,
    uint32_t* __restrict__ bcur, uint32_t* __restrict__ bbufE,
    uint32_t* __restrict__ bbufC, float* __restrict__ bbufV,
    uint32_t kd0a, uint32_t kd0b, uint32_t kd1a, uint32_t kd1b) {
  __shared__ uint32_t cnt[NB], cnt2[NB], gbase[NB];
  __shared__ uint32_t pref[NB + 1];
  __shared__ uint32_t stageE[TILE];
  __shared__ uint32_t stageC[TILE];
  __shared__ float    stageV[TILE];
  __shared__ uint16_t stageB[TILE];
  int tid = threadIdx.x;
  int base_e = blockIdx.x * TILE;
  int vcnt = NE - base_e; if (vcnt > TILE) vcnt = TILE;
  for (int j = tid; j < NB; j += 256) { cnt[j] = 0u; cnt2[j] = 0u; }
  __syncthreads();
  for (int i = tid; i < vcnt; i += 256) {
    uint32_t r = (uint32_t)rows[base_e + i];
    atomicAdd(&cnt[r >> 8], 1u);
  }
  __syncthreads();
  if (tid == 0) {
    uint32_t run = 0;
    for (int j = 0; j < NB; j++) { pref[j] = run; run += cnt[j]; }
    pref[NB] = run;
  }
  for (int j = tid; j < NB; j += 256) gbase[j] = atomicAdd(&bcur[j], cnt[j]);
  __syncthreads();
  for (int i = tid; i < vcnt; i += 256) {
    uint32_t e = (uint32_t)(base_e + i);
    uint32_t r = (uint32_t)rows[e];
    uint32_t b = r >> 8, lr = r & 255u;
    uint32_t m0 = (u01_from_key(kd0a, kd0b, e) >= 0.5f) ? 1u : 0u;
    uint32_t m1 = (u01_from_key(kd1a, kd1b, e) >= 0.75f) ? 1u : 0u;
    uint32_t flags = (m0 << 30) | ((m0 & m1) << 31);
    uint32_t slot = pref[b] + atomicAdd(&cnt2[b], 1u);
    stageE[slot] = flags | (lr << 22) | e;
    stageC[slot] = (uint32_t)cols[e];
    stageV[slot] = vals[e];
    stageB[slot] = (uint16_t)b;
  }
  __syncthreads();
  for (int i = tid; i < vcnt; i += 256) {
    uint32_t b = stageB[i];
    size_t dst = (size_t)b * CAP + gbase[b] + ((uint32_t)i - pref[b]);
    bbufE[dst] = stageE[i];
    bbufC[dst] = stageC[i];
    bbufV[dst] = stageV[i];
  }
}

// per-row counts (full / level-1 / level-2) from packed flags
__global__ void __launch_bounds__(256) k_cnt(const uint32_t* __restrict__ bcur,
    const uint32_t* __restrict__ bbufE, uint32_t* __restrict__ total,
    uint32_t* __restrict__ totalA, uint32_t* __restrict__ totalB) {
  __shared__ uint32_t c0[256], c1[256], c2[256];
  int b = blockIdx.x, tid = threadIdx.x;
  c0[tid] = 0u; c1[tid] = 0u; c2[tid] = 0u;
  __syncthreads();
  uint32_t nE = bcur[b];
  for (uint32_t i = tid; i < nE; i += 256) {
    uint32_t pk = bbufE[(size_t)b * CAP + i];
    uint32_t lr = (pk >> 22) & 255u;
    atomicAdd(&c0[lr], 1u);
    if (pk & 0x40000000u) atomicAdd(&c1[lr], 1u);
    if (pk & 0x80000000u) atomicAdd(&c2[lr], 1u);
  }
  __syncthreads();
  int row = (b << 8) + tid;
  if (row < NN) { total[row] = c0[tid]; totalA[row] = c1[tid]; totalB[row] = c2[tid]; }
}

// ---------------- scan (generic): rstart = exclusive prefix ----------------
__global__ void k_scan1(const uint32_t* __restrict__ total, uint32_t* __restrict__ rstart,
                        uint32_t* __restrict__ bsum) {
  __shared__ uint32_t s[1024];
  int i = blockIdx.x * 1024 + threadIdx.x;
  uint32_t v = (i < NN) ? total[i] : 0u;
  s[threadIdx.x] = v; __syncthreads();
  for (int o = 1; o < 1024; o <<= 1) {
    uint32_t x = (threadIdx.x >= (unsigned)o) ? s[threadIdx.x - o] : 0u;
    __syncthreads();
    s[threadIdx.x] += x;
    __syncthreads();
  }
  if (i <= NN) rstart[i] = s[threadIdx.x] - v;
  if (threadIdx.x == 1023) bsum[blockIdx.x] = s[1023];
}

__global__ void k_scan2(uint32_t* __restrict__ bsum) {
  if (blockIdx.x == 0 && threadIdx.x == 0) {
    uint32_t run = 0;
    for (int b = 0; b < SCAN_BLOCKS; b++) { uint32_t t = bsum[b]; bsum[b] = run; run += t; }
  }
}

__global__ void k_scan3(uint32_t* __restrict__ rstart, const uint32_t* __restrict__ bsum) {
  int i = blockIdx.x * 1024 + threadIdx.x;
  if (i <= NN) rstart[i] += bsum[blockIdx.x];
}

// ---------------- phase B: per-bucket stable CSR build + compaction --------
__global__ void __launch_bounds__(256) k_buildB(const uint32_t* __restrict__ bbufE,
    const uint32_t* __restrict__ bbufC, const float* __restrict__ bbufV,
    const uint32_t* __restrict__ rstart, const uint32_t* __restrict__ rstartA,
    const uint32_t* __restrict__ rstartB,
    uint32_t* __restrict__ scol, float* __restrict__ v0s,
    uint32_t* __restrict__ scolA, float* __restrict__ vAa,
    uint32_t* __restrict__ scolB, float* __restrict__ vBa,
    float* __restrict__ order0, float* __restrict__ order1) {
#pragma clang fp contract(off)
  __shared__ uint32_t eidp[CAP];
  __shared__ uint16_t slot[CAP];
  __shared__ uint32_t rbase[257];
  __shared__ uint32_t rcur[256];
  int b = blockIdx.x, tid = threadIdx.x;
  int row0 = b << 8;
  int nrows = NN - row0; if (nrows > 256) nrows = 256;
  uint32_t base = rstart[row0];
  for (int j = tid; j <= nrows; j += 256) rbase[j] = rstart[row0 + j] - base;
  rcur[tid] = 0u;
  __syncthreads();
  uint32_t nE = rbase[nrows];
  const uint32_t* bE = bbufE + (size_t)b * CAP;
  const uint32_t* bC = bbufC + (size_t)b * CAP;
  const float*    bV = bbufV + (size_t)b * CAP;
  // bin into per-row LDS lists (unordered)
  for (uint32_t i = tid; i < nE; i += 256) {
    uint32_t pk = bE[i];
    uint32_t lr = (pk >> 22) & 255u;
    uint32_t c = atomicAdd(&rcur[lr], 1u);
    uint32_t pos = rbase[lr] + c;
    eidp[pos] = pk;
    slot[pos] = (uint16_t)i;
  }
  __syncthreads();
  // restore stable (edge-id) order per row; mirror slot moves
  for (int lr = tid; lr < nrows; lr += 256) {
    uint32_t p0 = rbase[lr], p1 = rbase[lr + 1];
    for (uint32_t i = p0 + 1; i < p1; i++) {
      uint32_t key = eidp[i]; uint16_t ks = slot[i];
      uint32_t ke = key & 0x3FFFFFu;
      uint32_t j = i;
      while (j > p0 && (eidp[j - 1] & 0x3FFFFFu) > ke) {
        eidp[j] = eidp[j - 1]; slot[j] = slot[j - 1]; j--;
      }
      eidp[j] = key; slot[j] = ks;
    }
  }
  __syncthreads();
  // emit full arrays (coalesced writes; bC/bV slot reads are L1-local)
  for (uint32_t i = tid; i < nE; i += 256) {
    uint32_t s = slot[i];
    scol[(size_t)base + i] = bC[s];
    v0s[(size_t)base + i] = bV[s];
  }
  // per-row pass: compacted emits + rowsums in edge order (bit-identical:
  // skipped terms are exact +/-0 contributions)
  for (int lr = tid; lr < nrows; lr += 256) {
    uint32_t p0 = rbase[lr], p1 = rbase[lr + 1];
    uint32_t wA = rstartA[row0 + lr];
    uint32_t wB = rstartB[row0 + lr];
    float o0 = 0.0f, o1 = 0.0f;
    for (uint32_t p = p0; p < p1; p++) {
      uint32_t pk = eidp[p];
      uint32_t s = slot[p];
      float v = bV[s];
      o0 = o0 + v;
      if (pk & 0x40000000u) {
        o1 = o1 + v;
        uint32_t c = bC[s];
        scolA[wA] = c; vAa[wA] = v; wA++;
        if (pk & 0x80000000u) { scolB[wB] = c; vBa[wB] = v; wB++; }
      }
    }
    order0[row0 + lr] = o0; order1[row0 + lr] = o1;
  }
}

// ---------------- SpMM chain (wave per row, unroll-4 for MLP) --------------
// fst = spmm(vals0, embeds) - embeds
__global__ void __launch_bounds__(256) k_fst(const uint32_t* __restrict__ rp,
    const uint32_t* __restrict__ scol, const float* __restrict__ v0s,
    const float* __restrict__ emb, float* __restrict__ fst) {
#pragma clang fp contract(off)
  int r = blockIdx.x * 4 + (threadIdx.x >> 6);
  if (r >= NN) return;
  int d = threadIdx.x & 63;
  uint32_t p0 = rp[r], p1 = rp[r + 1];
  float acc = 0.0f;
  uint32_t p = p0;
  for (; p + 4 <= p1; p += 4) {
    uint32_t c0 = scol[p], c1 = scol[p + 1], c2 = scol[p + 2], c3 = scol[p + 3];
    float v0 = v0s[p], v1 = v0s[p + 1], v2 = v0s[p + 2], v3 = v0s[p + 3];
    float e0 = emb[(size_t)c0 * 64 + d];
    float e1 = emb[(size_t)c1 * 64 + d];
    float e2 = emb[(size_t)c2 * 64 + d];
    float e3 = emb[(size_t)c3 * 64 + d];
    acc = acc + v0 * e0; acc = acc + v1 * e1;
    acc = acc + v2 * e2; acc = acc + v3 * e3;
  }
  for (; p < p1; p++) acc = acc + v0s[p] * emb[(size_t)scol[p] * 64 + d];
  fst[(size_t)r * 64 + d] = acc - emb[(size_t)r * 64 + d];
}

// num0 = spmm(vals1, order0) - order0 - order0   (compact level-1 lists)
__global__ void __launch_bounds__(256) k_numA(const uint32_t* __restrict__ rpA,
    const uint32_t* __restrict__ scolA, const float* __restrict__ vAa,
    const float* __restrict__ order0, float* __restrict__ num0) {
#pragma clang fp contract(off)
  int r = blockIdx.x * blockDim.x + threadIdx.x;
  if (r >= NN) return;
  uint32_t p0 = rpA[r], p1 = rpA[r + 1];
  float acc = 0.0f;
  uint32_t p = p0;
  for (; p + 4 <= p1; p += 4) {
    uint32_t c0 = scolA[p], c1 = scolA[p + 1], c2 = scolA[p + 2], c3 = scolA[p + 3];
    float v0 = vAa[p], v1 = vAa[p + 1], v2 = vAa[p + 2], v3 = vAa[p + 3];
    float o0 = order0[c0], o1 = order0[c1], o2 = order0[c2], o3 = order0[c3];
    acc = acc + v0 * o0; acc = acc + v1 * o1;
    acc = acc + v2 * o2; acc = acc + v3 * o3;
  }
  for (; p < p1; p++) acc = acc + vAa[p] * order0[scolA[p]];
  float o = order0[r];
  num0[r] = (acc - o) - o;
}

// emb1 = spmm(vals1, fst) - fst - order0*fst     (compact level-1 lists)
__global__ void __launch_bounds__(256) k_emb1(const uint32_t* __restrict__ rpA,
    const uint32_t* __restrict__ scolA, const float* __restrict__ vAa,
    const float* __restrict__ fst, const float* __restrict__ order0,
    float* __restrict__ emb1) {
#pragma clang fp contract(off)
  int r = blockIdx.x * 4 + (threadIdx.x >> 6);
  if (r >= NN) return;
  int d = threadIdx.x & 63;
  uint32_t p0 = rpA[r], p1 = rpA[r + 1];
  float acc = 0.0f;
  uint32_t p = p0;
  for (; p + 4 <= p1; p += 4) {
    uint32_t c0 = scolA[p], c1 = scolA[p + 1], c2 = scolA[p + 2], c3 = scolA[p + 3];
    float v0 = vAa[p], v1 = vAa[p + 1], v2 = vAa[p + 2], v3 = vAa[p + 3];
    float e0 = fst[(size_t)c0 * 64 + d];
    float e1 = fst[(size_t)c1 * 64 + d];
    float e2 = fst[(size_t)c2 * 64 + d];
    float e3 = fst[(size_t)c3 * 64 + d];
    acc = acc + v0 * e0; acc = acc + v1 * e1;
    acc = acc + v2 * e2; acc = acc + v3 * e3;
  }
  for (; p < p1; p++) acc = acc + vAa[p] * fst[(size_t)scolA[p] * 64 + d];
  size_t i = (size_t)r * 64 + d;
  float pr = fst[i];
  float t  = order0[r] * pr;
  emb1[i] = (acc - pr) - t;
}

// num_sum = (order0 + num0) + ((spmm(vals2,num0) - num0) - order1)
__global__ void __launch_bounds__(256) k_numB(const uint32_t* __restrict__ rpB,
    const uint32_t* __restrict__ scolB, const float* __restrict__ vBa,
    const float* __restrict__ num0, const float* __restrict__ order0,
    const float* __restrict__ order1, float* __restrict__ num_sum) {
#pragma clang fp contract(off)
  int r = blockIdx.x * blockDim.x + threadIdx.x;
  if (r >= NN) return;
  uint32_t p0 = rpB[r], p1 = rpB[r + 1];
  float acc = 0.0f;
  for (uint32_t p = p0; p < p1; p++) acc = acc + vBa[p] * num0[scolB[p]];
  float n1 = (acc - num0[r]) - order1[r];
  num_sum[r] = (order0[r] + num0[r]) + n1;
}

// esum = (fst + emb1) + ((spmm(vals2,emb1) - emb1) - order1*emb1); into fst
__global__ void __launch_bounds__(256) k_emb2(const uint32_t* __restrict__ rpB,
    const uint32_t* __restrict__ scolB, const float* __restrict__ vBa,
    const float* __restrict__ emb1, const float* __restrict__ order1,
    float* __restrict__ fstsum) {
#pragma clang fp contract(off)
  int r = blockIdx.x * 4 + (threadIdx.x >> 6);
  if (r >= NN) return;
  int d = threadIdx.x & 63;
  uint32_t p0 = rpB[r], p1 = rpB[r + 1];
  float acc = 0.0f;
  uint32_t p = p0;
  for (; p + 4 <= p1; p += 4) {
    uint32_t c0 = scolB[p], c1 = scolB[p + 1], c2 = scolB[p + 2], c3 = scolB[p + 3];
    float v0 = vBa[p], v1 = vBa[p + 1], v2 = vBa[p + 2], v3 = vBa[p + 3];
    float e0 = emb1[(size_t)c0 * 64 + d];
    float e1 = emb1[(size_t)c1 * 64 + d];
    float e2 = emb1[(size_t)c2 * 64 + d];
    float e3 = emb1[(size_t)c3 * 64 + d];
    acc = acc + v0 * e0; acc = acc + v1 * e1;
    acc = acc + v2 * e2; acc = acc + v3 * e3;
  }
  for (; p < p1; p++) acc = acc + vBa[p] * emb1[(size_t)scolB[p] * 64 + d];
  size_t i = (size_t)r * 64 + d;
  float pr = emb1[i];
  float t  = order1[r] * pr;
  float e2v = (acc - pr) - t;
  fstsum[i] = (fstsum[i] + pr) + e2v;
}

// ---------------- scores: one wave per row, exact numpy trees --------------
__global__ void __launch_bounds__(256) k_scores(const float* __restrict__ esum,
    const float* __restrict__ num_sum, const float* __restrict__ emb,
    uint32_t* __restrict__ m_arr, float* __restrict__ out_scores,
    uint32_t kna, uint32_t knb) {
#pragma clang fp contract(off)
  int r = blockIdx.x * 4 + (threadIdx.x >> 6);
  if (r >= NN) return;
  int lane = threadIdx.x & 63;
  size_t ib = (size_t)r * 64 + lane;
  float denom = num_sum[r] + 1e-8f;
  float t = esum[ib] / denom;
  float S1 = np_tree64(t * t);
  float nn = fmaxf(sqrtf(S1), 1e-12f);
  t = t / nn;
  float e = emb[ib];
  float S2 = np_tree64(e * e);
  float mn = fmaxf(sqrtf(S2), 1e-12f);
  float s = np_tree64(t * (e / mn));
  if (lane == 0) {
    float u  = u01_from_key(kna, knb, (uint32_t)r);
    float l1 = (float)log((double)u);
    float l2 = (float)log((double)(-l1));
    s = s + (-l2);
    uint32_t bb = __float_as_uint(s);
    m_arr[r] = bb ^ (uint32_t)(((int32_t)bb >> 31) | (int32_t)0x80000000);
    out_scores[r] = s;
  }
}

// ---------------- grid-parallel exact top-1024 ----------------
// Single 16-bit histogram pass (global atomics, 65536 bins -> low contention),
// serial suffix-select at 16-bit granularity, over-collect boundary bin,
// exact 32-bit sort in one block. Replaces the single-CU 5-pass k_topk
// (156 us, issue-rate bound on one CU).
__global__ void __launch_bounds__(1024) k_h16(const uint32_t* __restrict__ m_arr,
                                              uint32_t* __restrict__ hist16) {
  int i = blockIdx.x * 1024 + threadIdx.x;
  if (i < NN) atomicAdd(&hist16[m_arr[i] >> 16], 1u);
}

__global__ void __launch_bounds__(1024) k_sel16(const uint32_t* __restrict__ hist16,
                                                uint32_t* __restrict__ selthr) {
  __shared__ uint32_t part[1024];
  int t = threadIdx.x;
  uint32_t s = 0;
  for (int j = 0; j < 64; j++) s += hist16[t * 64 + j];
  part[t] = s;
  __syncthreads();
  if (t == 0) {
    uint32_t acc = 0;
    int c = 1023;
    for (; c >= 0; c--) {
      if (acc + part[c] >= (uint32_t)NCAND) break;
      acc += part[c];
    }
    uint32_t thr = 0;
    if (c >= 0) {
      int b = c * 64 + 63;
      for (; b >= c * 64; b--) { acc += hist16[b]; if (acc >= (uint32_t)NCAND) break; }
      thr = (uint32_t)b << 16;
    }
    selthr[0] = thr;
  }
}

__global__ void __launch_bounds__(256) k_collect(const uint32_t* __restrict__ m_arr,
    const uint32_t* __restrict__ selthr, unsigned long long* __restrict__ cbuf,
    uint32_t* __restrict__ ccnt) {
  int i = blockIdx.x * blockDim.x + threadIdx.x;
  int stride = gridDim.x * blockDim.x;
  uint32_t thr = selthr[0];
  for (; i < NN; i += stride) {
    uint32_t m = m_arr[i];
    if (m >= thr) {
      uint32_t pos = atomicAdd(ccnt, 1u);   // wave-coalesced by compiler
      if (pos < 4096u)
        cbuf[pos] = ((unsigned long long)m << 32) | (uint32_t)(~(uint32_t)i);
    }
  }
}

__global__ void __launch_bounds__(1024) k_sortemit(
    const unsigned long long* __restrict__ gcbuf, const uint32_t* __restrict__ ccnt,
    float* __restrict__ out) {
  __shared__ unsigned long long cbuf[4096];
  int tid = threadIdx.x;
  uint32_t n = *ccnt; if (n > 4096u) n = 4096u;
  for (int i = tid; i < 4096; i += 1024) cbuf[i] = (i < (int)n) ? gcbuf[i] : 0ULL;
  __syncthreads();
  for (int k = 2; k <= 4096; k <<= 1) {
    for (int j = k >> 1; j > 0; j >>= 1) {
      for (int i = tid; i < 4096; i += 1024) {
        int ixj = i ^ j;
        if (ixj > i) {
          bool up = ((i & k) == 0);
          unsigned long long a = cbuf[i], b = cbuf[ixj];
          if ((a > b) == up) { cbuf[i] = b; cbuf[ixj] = a; }
        }
      }
      __syncthreads();
    }
  }
  for (int j = tid; j < NCAND; j += 1024) {
    unsigned long long key = cbuf[4095 - j];
    uint32_t idx = ~(uint32_t)(key & 0xFFFFFFFFull);
    out[j] = (float)idx;
  }
}

// ---------------- launcher ----------------
extern "C" void kernel_launch(void* const* d_in, const int* in_sizes, int n_in,
                              void* d_out, int out_size, void* d_ws, size_t ws_size,
                              hipStream_t stream) {
  (void)in_sizes; (void)n_in; (void)out_size; (void)ws_size;
  const int*   rows = (const int*)d_in[0];
  const int*   cols = (const int*)d_in[1];
  const float* vals = (const float*)d_in[2];
  const float* emb  = (const float*)d_in[3];
  float* out = (float*)d_out;   // f32: scores[NN] then candidates[1024]

  char* w = (char*)d_ws;
  auto alloc = [&](size_t bytes) -> void* {
    void* p = (void*)w; w += (bytes + 255) & ~(size_t)255; return p;
  };
  uint32_t* bcur    = (uint32_t*)alloc((size_t)NB * 4);
  uint32_t* bbufE   = (uint32_t*)alloc((size_t)NB * CAP * 4);
  uint32_t* bbufC   = (uint32_t*)alloc((size_t)NB * CAP * 4);
  float*    bbufV   = (float*)   alloc((size_t)NB * CAP * 4);
  uint32_t* total   = (uint32_t*)alloc((size_t)NN * 4);
  uint32_t* totalA  = (uint32_t*)alloc((size_t)NN * 4);
  uint32_t* totalB  = (uint32_t*)alloc((size_t)NN * 4);
  uint32_t* rstart  = (uint32_t*)alloc((size_t)(NN + 1) * 4);
  uint32_t* rstartA = (uint32_t*)alloc((size_t)(NN + 1) * 4);
  uint32_t* rstartB = (uint32_t*)alloc((size_t)(NN + 1) * 4);
  uint32_t* bsum    = (uint32_t*)alloc((size_t)SCAN_BLOCKS * 4);
  uint32_t* scol    = (uint32_t*)alloc((size_t)NE * 4);
  float*    v0s     = (float*)   alloc((size_t)NE * 4);
  uint32_t* scolA   = (uint32_t*)alloc((size_t)NA_CAP * 4);
  float*    vAa     = (float*)   alloc((size_t)NA_CAP * 4);
  uint32_t* scolB   = (uint32_t*)alloc((size_t)NB_CAP * 4);
  float*    vBa     = (float*)   alloc((size_t)NB_CAP * 4);
  float*    order0  = (float*)   alloc((size_t)NN * 4);
  float*    order1  = (float*)   alloc((size_t)NN * 4);
  float*    num0    = (float*)   alloc((size_t)NN * 4);
  float*    num_sum = (float*)   alloc((size_t)NN * 4);
  float*    fst     = (float*)   alloc((size_t)NN * 64 * 4);
  float*    emb1    = (float*)   alloc((size_t)NN * 64 * 4);
  uint32_t* m_arr   = (uint32_t*)alloc((size_t)NN * 4);
  uint32_t* hist16  = (uint32_t*)alloc((size_t)HBINS * 4);
  uint32_t* selthr  = (uint32_t*)alloc(4);
  uint32_t* gccnt   = (uint32_t*)alloc(4);
  unsigned long long* gcbuf = (unsigned long long*)alloc(4096 * 8);

  // host-side threefry key chain (data-independent)
  uint32_t K1a,K1b, kd0a,kd0b, K2a,K2b, kd1a,kd1b, kna,knb;
  tf2x32(0u, 42u, 0u, 0u, K1a, K1b);
  tf2x32(0u, 42u, 0u, 1u, kd0a, kd0b);
  tf2x32(K1a, K1b, 0u, 0u, K2a, K2b);
  tf2x32(K1a, K1b, 0u, 1u, kd1a, kd1b);
  tf2x32(K2a, K2b, 0u, 1u, kna, knb);

  hipMemsetAsync(bcur, 0, (size_t)NB * 4, stream);
  hipMemsetAsync(hist16, 0, (size_t)HBINS * 4, stream);
  hipMemsetAsync(gccnt, 0, 4, stream);

  const int TPB = 256;
  k_bucketA<<<(NE + TILE - 1) / TILE, TPB, 0, stream>>>(rows, cols, vals, bcur,
      bbufE, bbufC, bbufV, kd0a, kd0b, kd1a, kd1b);
  k_cnt<<<NB, TPB, 0, stream>>>(bcur, bbufE, total, totalA, totalB);
  k_scan1<<<SCAN_BLOCKS, 1024, 0, stream>>>(total, rstart, bsum);
  k_scan2<<<1, 1, 0, stream>>>(bsum);
  k_scan3<<<SCAN_BLOCKS, 1024, 0, stream>>>(rstart, bsum);
  k_scan1<<<SCAN_BLOCKS, 1024, 0, stream>>>(totalA, rstartA, bsum);
  k_scan2<<<1, 1, 0, stream>>>(bsum);
  k_scan3<<<SCAN_BLOCKS, 1024, 0, stream>>>(rstartA, bsum);
  k_scan1<<<SCAN_BLOCKS, 1024, 0, stream>>>(totalB, rstartB, bsum);
  k_scan2<<<1, 1, 0, stream>>>(bsum);
  k_scan3<<<SCAN_BLOCKS, 1024, 0, stream>>>(rstartB, bsum);
  k_buildB<<<NB, TPB, 0, stream>>>(bbufE, bbufC, bbufV, rstart, rstartA, rstartB,
      scol, v0s, scolA, vAa, scolB, vBa, order0, order1);
  k_fst<<<(NN + 3) / 4, TPB, 0, stream>>>(rstart, scol, v0s, emb, fst);
  k_numA<<<(NN + TPB - 1) / TPB, TPB, 0, stream>>>(rstartA, scolA, vAa, order0, num0);
  k_emb1<<<(NN + 3) / 4, TPB, 0, stream>>>(rstartA, scolA, vAa, fst, order0, emb1);
  k_numB<<<(NN + TPB - 1) / TPB, TPB, 0, stream>>>(rstartB, scolB, vBa, num0, order0, order1, num_sum);
  k_emb2<<<(NN + 3) / 4, TPB, 0, stream>>>(rstartB, scolB, vBa, emb1, order1, fst);
  k_scores<<<(NN + 3) / 4, TPB, 0, stream>>>(fst, num_sum, emb, m_arr, out, kna, knb);
  k_h16<<<(NN + 1023) / 1024, 1024, 0, stream>>>(m_arr, hist16);
  k_sel16<<<1, 1024, 0, stream>>>(hist16, selthr);
  k_collect<<<64, TPB, 0, stream>>>(m_arr, selthr, gcbuf, gccnt);
  k_sortemit<<<1, 1024, 0, stream>>>(gcbuf, gccnt, out + NN);
}

// Round 9
// 786.698 us; speedup vs baseline: 1.9544x; 1.0309x over previous
//
#include <hip/hip_runtime.h>
#include <hip/hip_bf16.h>
#include <stdint.h>
#include <stddef.h>

// Problem constants (fixed by the reference)
#define NN 100000          // nodes
#define NE 3200000         // edges
#define NCAND 1024
#define SCAN_BLOCKS 98     // ceil((NN+1)/1024)
#define NB 391             // buckets of 256 rows: ceil(100000/256)
#define CAP 10240          // bucket capacity (mean 8184, +22 sigma)
#define TILE 4096          // edges per bucketA block (LDS: 3 staged words)
#define NA_CAP 1700000     // level-1 compact bound (mean 1.6M, +100 sigma)
#define NB_CAP 500000      // level-2 compact bound (mean 400k, +84 sigma)
#define HBINS 65536

// ---------------- threefry2x32, exact JAX lowering ----------------
__host__ __device__ inline void tf2x32(uint32_t k0, uint32_t k1,
                                       uint32_t x0, uint32_t x1,
                                       uint32_t& y0, uint32_t& y1) {
  uint32_t ks2 = k0 ^ k1 ^ 0x1BD11BDAu;
  x0 += k0; x1 += k1;
#define TFR(r) { x0 += x1; x1 = (x1 << (r)) | (x1 >> (32 - (r))); x1 ^= x0; }
  TFR(13) TFR(15) TFR(26) TFR(6)
  x0 += k1;  x1 += ks2 + 1u;
  TFR(17) TFR(29) TFR(16) TFR(24)
  x0 += ks2; x1 += k0 + 2u;
  TFR(13) TFR(15) TFR(26) TFR(6)
  x0 += k0;  x1 += k1 + 3u;
  TFR(17) TFR(29) TFR(16) TFR(24)
  x0 += k1;  x1 += ks2 + 4u;
  TFR(13) TFR(15) TFR(26) TFR(6)
  x0 += ks2; x1 += k0 + 5u;
#undef TFR
  y0 = x0; y1 = x1;
}

__device__ inline float u01_from_key(uint32_t ka, uint32_t kb, uint32_t idx) {
  uint32_t y0, y1; tf2x32(ka, kb, 0u, idx, y0, y1);
  uint32_t bits = y0 ^ y1;
  return __uint_as_float((bits >> 9) | 0x3F800000u) - 1.0f;
}

// exact numpy pairwise-64 tree via wave shuffles
__device__ inline float np_tree64(float w) {
#pragma clang fp contract(off)
  float acc = w;
  acc = acc + __shfl_down(w, 8);
  acc = acc + __shfl_down(w, 16);
  acc = acc + __shfl_down(w, 24);
  acc = acc + __shfl_down(w, 32);
  acc = acc + __shfl_down(w, 40);
  acc = acc + __shfl_down(w, 48);
  acc = acc + __shfl_down(w, 56);
  float u = acc + __shfl_xor(acc, 1);
  float v = u + __shfl_xor(u, 2);
  float f = v + __shfl_xor(v, 4);
  return __shfl(f, 0);
}

// ---------------- phase A: bucket edges by row>>8, carrying col/val --------
// bbufE[b*CAP+k] = (bothmask<<31)|(m0<<30)|(lr<<22)|e ; bbufC/bbufV parallel.
__global__ void __launch_bounds__(256) k_bucketA(const int* __restrict__ rows,
    const int* __restrict__ cols, const float* __restrict__ vals,
    uint32_t* __restrict__ bcur, uint32_t* __restrict__ bbufE,
    uint32_t* __restrict__ bbufC, float* __restrict__ bbufV,
    uint32_t kd0a, uint32_t kd0b, uint32_t kd1a, uint32_t kd1b) {
  __shared__ uint32_t cnt[NB], cnt2[NB], gbase[NB];
  __shared__ uint32_t pref[NB + 1];
  __shared__ uint32_t stageE[TILE];
  __shared__ uint32_t stageC[TILE];
  __shared__ float    stageV[TILE];
  __shared__ uint16_t stageB[TILE];
  int tid = threadIdx.x;
  int base_e = blockIdx.x * TILE;
  int vcnt = NE - base_e; if (vcnt > TILE) vcnt = TILE;
  for (int j = tid; j < NB; j += 256) { cnt[j] = 0u; cnt2[j] = 0u; }
  __syncthreads();
  for (int i = tid; i < vcnt; i += 256) {
    uint32_t r = (uint32_t)rows[base_e + i];
    atomicAdd(&cnt[r >> 8], 1u);
  }
  __syncthreads();
  if (tid == 0) {
    uint32_t run = 0;
    for (int j = 0; j < NB; j++) { pref[j] = run; run += cnt[j]; }
    pref[NB] = run;
  }
  for (int j = tid; j < NB; j += 256) gbase[j] = atomicAdd(&bcur[j], cnt[j]);
  __syncthreads();
  for (int i = tid; i < vcnt; i += 256) {
    uint32_t e = (uint32_t)(base_e + i);
    uint32_t r = (uint32_t)rows[e];
    uint32_t b = r >> 8, lr = r & 255u;
    uint32_t m0 = (u01_from_key(kd0a, kd0b, e) >= 0.5f) ? 1u : 0u;
    uint32_t m1 = (u01_from_key(kd1a, kd1b, e) >= 0.75f) ? 1u : 0u;
    uint32_t flags = (m0 << 30) | ((m0 & m1) << 31);
    uint32_t slot = pref[b] + atomicAdd(&cnt2[b], 1u);
    stageE[slot] = flags | (lr << 22) | e;
    stageC[slot] = (uint32_t)cols[e];
    stageV[slot] = vals[e];
    stageB[slot] = (uint16_t)b;
  }
  __syncthreads();
  for (int i = tid; i < vcnt; i += 256) {
    uint32_t b = stageB[i];
    size_t dst = (size_t)b * CAP + gbase[b] + ((uint32_t)i - pref[b]);
    bbufE[dst] = stageE[i];
    bbufC[dst] = stageC[i];
    bbufV[dst] = stageV[i];
  }
}

// per-row counts (full / level-1 / level-2) from packed flags
__global__ void __launch_bounds__(256) k_cnt(const uint32_t* __restrict__ bcur,
    const uint32_t* __restrict__ bbufE, uint32_t* __restrict__ total,
    uint32_t* __restrict__ totalA, uint32_t* __restrict__ totalB) {
  __shared__ uint32_t c0[256], c1[256], c2[256];
  int b = blockIdx.x, tid = threadIdx.x;
  c0[tid] = 0u; c1[tid] = 0u; c2[tid] = 0u;
  __syncthreads();
  uint32_t nE = bcur[b];
  for (uint32_t i = tid; i < nE; i += 256) {
    uint32_t pk = bbufE[(size_t)b * CAP + i];
    uint32_t lr = (pk >> 22) & 255u;
    atomicAdd(&c0[lr], 1u);
    if (pk & 0x40000000u) atomicAdd(&c1[lr], 1u);
    if (pk & 0x80000000u) atomicAdd(&c2[lr], 1u);
  }
  __syncthreads();
  int row = (b << 8) + tid;
  if (row < NN) { total[row] = c0[tid]; totalA[row] = c1[tid]; totalB[row] = c2[tid]; }
}

// ---------------- scans: 3 arrays in one launch via gridDim.y -------------
__global__ void k_scan1(const uint32_t* __restrict__ t0, const uint32_t* __restrict__ t1,
                        const uint32_t* __restrict__ t2, uint32_t* __restrict__ r0,
                        uint32_t* __restrict__ r1, uint32_t* __restrict__ r2,
                        uint32_t* __restrict__ bsum) {
  __shared__ uint32_t s[1024];
  const uint32_t* in = (blockIdx.y == 0) ? t0 : (blockIdx.y == 1) ? t1 : t2;
  uint32_t* out = (blockIdx.y == 0) ? r0 : (blockIdx.y == 1) ? r1 : r2;
  uint32_t* bs = bsum + blockIdx.y * SCAN_BLOCKS;
  int i = blockIdx.x * 1024 + threadIdx.x;
  uint32_t v = (i < NN) ? in[i] : 0u;
  s[threadIdx.x] = v; __syncthreads();
  for (int o = 1; o < 1024; o <<= 1) {
    uint32_t x = (threadIdx.x >= (unsigned)o) ? s[threadIdx.x - o] : 0u;
    __syncthreads();
    s[threadIdx.x] += x;
    __syncthreads();
  }
  if (i <= NN) out[i] = s[threadIdx.x] - v;
  if (threadIdx.x == 1023) bs[blockIdx.x] = s[1023];
}

__global__ void k_scan2(uint32_t* __restrict__ bsum) {
  int y = threadIdx.x;   // 3 threads, one array each
  if (y < 3) {
    uint32_t* bs = bsum + y * SCAN_BLOCKS;
    uint32_t run = 0;
    for (int b = 0; b < SCAN_BLOCKS; b++) { uint32_t t = bs[b]; bs[b] = run; run += t; }
  }
}

__global__ void k_scan3(uint32_t* __restrict__ r0, uint32_t* __restrict__ r1,
                        uint32_t* __restrict__ r2, const uint32_t* __restrict__ bsum) {
  uint32_t* out = (blockIdx.y == 0) ? r0 : (blockIdx.y == 1) ? r1 : r2;
  const uint32_t* bs = bsum + blockIdx.y * SCAN_BLOCKS;
  int i = blockIdx.x * 1024 + threadIdx.x;
  if (i <= NN) out[i] += bs[blockIdx.x];
}

// ---------------- phase B: per-bucket stable CSR build + compaction --------
// Compact A/B emits via bucket-level ballot compaction (coalesced writes;
// round-8 profile: per-row serial emit caused 3.5x write amplification).
__global__ void __launch_bounds__(256) k_buildB(const uint32_t* __restrict__ bbufE,
    const uint32_t* __restrict__ bbufC, const float* __restrict__ bbufV,
    const uint32_t* __restrict__ rstart, const uint32_t* __restrict__ rstartA,
    const uint32_t* __restrict__ rstartB,
    uint32_t* __restrict__ scol, float* __restrict__ v0s,
    uint32_t* __restrict__ scolA, float* __restrict__ vAa,
    uint32_t* __restrict__ scolB, float* __restrict__ vBa,
    float* __restrict__ order0, float* __restrict__ order1) {
#pragma clang fp contract(off)
  __shared__ uint32_t eidp[CAP];
  __shared__ uint16_t slot[CAP];
  __shared__ uint32_t rbase[257];
  __shared__ uint32_t rcur[256];
  __shared__ uint32_t wsumA[4], wsumB[4];
  int b = blockIdx.x, tid = threadIdx.x;
  int wave = tid >> 6, lane = tid & 63;
  unsigned long long lmask = (1ULL << lane) - 1ULL;
  int row0 = b << 8;
  int nrows = NN - row0; if (nrows > 256) nrows = 256;
  uint32_t base = rstart[row0];
  for (int j = tid; j <= nrows; j += 256) rbase[j] = rstart[row0 + j] - base;
  rcur[tid] = 0u;
  __syncthreads();
  uint32_t nE = rbase[nrows];
  const uint32_t* bC = bbufC + (size_t)b * CAP;
  const float*    bV = bbufV + (size_t)b * CAP;
  const uint32_t* bE = bbufE + (size_t)b * CAP;
  // bin into per-row LDS lists (unordered)
  for (uint32_t i = tid; i < nE; i += 256) {
    uint32_t pk = bE[i];
    uint32_t lr = (pk >> 22) & 255u;
    uint32_t c = atomicAdd(&rcur[lr], 1u);
    uint32_t pos = rbase[lr] + c;
    eidp[pos] = pk;
    slot[pos] = (uint16_t)i;
  }
  __syncthreads();
  // restore stable (edge-id) order per row; mirror slot moves
  for (int lr = tid; lr < nrows; lr += 256) {
    uint32_t p0 = rbase[lr], p1 = rbase[lr + 1];
    for (uint32_t i = p0 + 1; i < p1; i++) {
      uint32_t key = eidp[i]; uint16_t ks = slot[i];
      uint32_t ke = key & 0x3FFFFFu;
      uint32_t j = i;
      while (j > p0 && (eidp[j - 1] & 0x3FFFFFu) > ke) {
        eidp[j] = eidp[j - 1]; slot[j] = slot[j - 1]; j--;
      }
      eidp[j] = key; slot[j] = ks;
    }
  }
  __syncthreads();
  // emit full arrays (coalesced writes; bC/bV slot reads are L1-local)
  for (uint32_t i = tid; i < nE; i += 256) {
    uint32_t s = slot[i];
    scol[(size_t)base + i] = bC[s];
    v0s[(size_t)base + i] = bV[s];
  }
  // --- bucket-level ballot compaction for A/B lists (order-preserving) ---
  uint32_t quarter = (nE + 3u) >> 2;
  uint32_t w0 = (uint32_t)wave * quarter;
  uint32_t w1 = w0 + quarter; if (w1 > nE) w1 = nE;
  // count pass
  uint32_t cA = 0, cB = 0;
  for (uint32_t gbase2 = w0; gbase2 < w1; gbase2 += 64) {
    uint32_t i = gbase2 + (uint32_t)lane;
    bool v = i < w1;
    uint32_t pk = v ? eidp[i] : 0u;
    unsigned long long ba = __ballot(v && (pk & 0x40000000u));
    unsigned long long bb = __ballot(v && (pk & 0x80000000u));
    cA += (uint32_t)__popcll(ba);
    cB += (uint32_t)__popcll(bb);
  }
  if (lane == 0) { wsumA[wave] = cA; wsumB[wave] = cB; }
  __syncthreads();
  if (tid == 0) {
    uint32_t a = 0, b2 = 0;
    for (int w2 = 0; w2 < 4; w2++) {
      uint32_t ta = wsumA[w2], tb = wsumB[w2];
      wsumA[w2] = a; wsumB[w2] = b2;
      a += ta; b2 += tb;
    }
  }
  __syncthreads();
  uint32_t curA = rstartA[row0] + wsumA[wave];
  uint32_t curB = rstartB[row0] + wsumB[wave];
  for (uint32_t gbase2 = w0; gbase2 < w1; gbase2 += 64) {
    uint32_t i = gbase2 + (uint32_t)lane;
    bool v = i < w1;
    uint32_t pk = v ? eidp[i] : 0u;
    uint32_t s = v ? slot[i] : 0u;
    unsigned long long ba = __ballot(v && (pk & 0x40000000u));
    unsigned long long bb = __ballot(v && (pk & 0x80000000u));
    if (v && (pk & 0x40000000u)) {
      uint32_t pos = curA + (uint32_t)__popcll(ba & lmask);
      scolA[pos] = bC[s]; vAa[pos] = bV[s];
    }
    if (v && (pk & 0x80000000u)) {
      uint32_t pos = curB + (uint32_t)__popcll(bb & lmask);
      scolB[pos] = bC[s]; vBa[pos] = bV[s];
    }
    curA += (uint32_t)__popcll(ba);
    curB += (uint32_t)__popcll(bb);
  }
  // rowsums in edge order (reads only; writes tiny)
  for (int lr = tid; lr < nrows; lr += 256) {
    uint32_t p0 = rbase[lr], p1 = rbase[lr + 1];
    float o0 = 0.0f, o1 = 0.0f;
    for (uint32_t p = p0; p < p1; p++) {
      uint32_t pk = eidp[p];
      float v = bV[slot[p]];
      o0 = o0 + v;
      if (pk & 0x40000000u) o1 = o1 + v;
    }
    order0[row0 + lr] = o0; order1[row0 + lr] = o1;
  }
}

// ---------------- SpMM chain (wave per row, unroll-4 for MLP) --------------
// fst = spmm(vals0, embeds) - embeds
__global__ void __launch_bounds__(256) k_fst(const uint32_t* __restrict__ rp,
    const uint32_t* __restrict__ scol, const float* __restrict__ v0s,
    const float* __restrict__ emb, float* __restrict__ fst) {
#pragma clang fp contract(off)
  int r = blockIdx.x * 4 + (threadIdx.x >> 6);
  if (r >= NN) return;
  int d = threadIdx.x & 63;
  uint32_t p0 = rp[r], p1 = rp[r + 1];
  float acc = 0.0f;
  uint32_t p = p0;
  for (; p + 4 <= p1; p += 4) {
    uint32_t c0 = scol[p], c1 = scol[p + 1], c2 = scol[p + 2], c3 = scol[p + 3];
    float v0 = v0s[p], v1 = v0s[p + 1], v2 = v0s[p + 2], v3 = v0s[p + 3];
    float e0 = emb[(size_t)c0 * 64 + d];
    float e1 = emb[(size_t)c1 * 64 + d];
    float e2 = emb[(size_t)c2 * 64 + d];
    float e3 = emb[(size_t)c3 * 64 + d];
    acc = acc + v0 * e0; acc = acc + v1 * e1;
    acc = acc + v2 * e2; acc = acc + v3 * e3;
  }
  for (; p < p1; p++) acc = acc + v0s[p] * emb[(size_t)scol[p] * 64 + d];
  fst[(size_t)r * 64 + d] = acc - emb[(size_t)r * 64 + d];
}

// num0 = spmm(vals1, order0) - order0 - order0   (compact level-1 lists)
__global__ void __launch_bounds__(256) k_numA(const uint32_t* __restrict__ rpA,
    const uint32_t* __restrict__ scolA, const float* __restrict__ vAa,
    const float* __restrict__ order0, float* __restrict__ num0) {
#pragma clang fp contract(off)
  int r = blockIdx.x * blockDim.x + threadIdx.x;
  if (r >= NN) return;
  uint32_t p0 = rpA[r], p1 = rpA[r + 1];
  float acc = 0.0f;
  uint32_t p = p0;
  for (; p + 4 <= p1; p += 4) {
    uint32_t c0 = scolA[p], c1 = scolA[p + 1], c2 = scolA[p + 2], c3 = scolA[p + 3];
    float v0 = vAa[p], v1 = vAa[p + 1], v2 = vAa[p + 2], v3 = vAa[p + 3];
    float o0 = order0[c0], o1 = order0[c1], o2 = order0[c2], o3 = order0[c3];
    acc = acc + v0 * o0; acc = acc + v1 * o1;
    acc = acc + v2 * o2; acc = acc + v3 * o3;
  }
  for (; p < p1; p++) acc = acc + vAa[p] * order0[scolA[p]];
  float o = order0[r];
  num0[r] = (acc - o) - o;
}

// emb1 = spmm(vals1, fst) - fst - order0*fst     (compact level-1 lists)
__global__ void __launch_bounds__(256) k_emb1(const uint32_t* __restrict__ rpA,
    const uint32_t* __restrict__ scolA, const float* __restrict__ vAa,
    const float* __restrict__ fst, const float* __restrict__ order0,
    float* __restrict__ emb1) {
#pragma clang fp contract(off)
  int r = blockIdx.x * 4 + (threadIdx.x >> 6);
  if (r >= NN) return;
  int d = threadIdx.x & 63;
  uint32_t p0 = rpA[r], p1 = rpA[r + 1];
  float acc = 0.0f;
  uint32_t p = p0;
  for (; p + 4 <= p1; p += 4) {
    uint32_t c0 = scolA[p], c1 = scolA[p + 1], c2 = scolA[p + 2], c3 = scolA[p + 3];
    float v0 = vAa[p], v1 = vAa[p + 1], v2 = vAa[p + 2], v3 = vAa[p + 3];
    float e0 = fst[(size_t)c0 * 64 + d];
    float e1 = fst[(size_t)c1 * 64 + d];
    float e2 = fst[(size_t)c2 * 64 + d];
    float e3 = fst[(size_t)c3 * 64 + d];
    acc = acc + v0 * e0; acc = acc + v1 * e1;
    acc = acc + v2 * e2; acc = acc + v3 * e3;
  }
  for (; p < p1; p++) acc = acc + vAa[p] * fst[(size_t)scolA[p] * 64 + d];
  size_t i = (size_t)r * 64 + d;
  float pr = fst[i];
  float t  = order0[r] * pr;
  emb1[i] = (acc - pr) - t;
}

// num_sum = (order0 + num0) + ((spmm(vals2,num0) - num0) - order1)
__global__ void __launch_bounds__(256) k_numB(const uint32_t* __restrict__ rpB,
    const uint32_t* __restrict__ scolB, const float* __restrict__ vBa,
    const float* __restrict__ num0, const float* __restrict__ order0,
    const float* __restrict__ order1, float* __restrict__ num_sum) {
#pragma clang fp contract(off)
  int r = blockIdx.x * blockDim.x + threadIdx.x;
  if (r >= NN) return;
  uint32_t p0 = rpB[r], p1 = rpB[r + 1];
  float acc = 0.0f;
  for (uint32_t p = p0; p < p1; p++) acc = acc + vBa[p] * num0[scolB[p]];
  float n1 = (acc - num0[r]) - order1[r];
  num_sum[r] = (order0[r] + num0[r]) + n1;
}

// esum = (fst + emb1) + ((spmm(vals2,emb1) - emb1) - order1*emb1); into fst
__global__ void __launch_bounds__(256) k_emb2(const uint32_t* __restrict__ rpB,
    const uint32_t* __restrict__ scolB, const float* __restrict__ vBa,
    const float* __restrict__ emb1, const float* __restrict__ order1,
    float* __restrict__ fstsum) {
#pragma clang fp contract(off)
  int r = blockIdx.x * 4 + (threadIdx.x >> 6);
  if (r >= NN) return;
  int d = threadIdx.x & 63;
  uint32_t p0 = rpB[r], p1 = rpB[r + 1];
  float acc = 0.0f;
  uint32_t p = p0;
  for (; p + 4 <= p1; p += 4) {
    uint32_t c0 = scolB[p], c1 = scolB[p + 1], c2 = scolB[p + 2], c3 = scolB[p + 3];
    float v0 = vBa[p], v1 = vBa[p + 1], v2 = vBa[p + 2], v3 = vBa[p + 3];
    float e0 = emb1[(size_t)c0 * 64 + d];
    float e1 = emb1[(size_t)c1 * 64 + d];
    float e2 = emb1[(size_t)c2 * 64 + d];
    float e3 = emb1[(size_t)c3 * 64 + d];
    acc = acc + v0 * e0; acc = acc + v1 * e1;
    acc = acc + v2 * e2; acc = acc + v3 * e3;
  }
  for (; p < p1; p++) acc = acc + vBa[p] * emb1[(size_t)scolB[p] * 64 + d];
  size_t i = (size_t)r * 64 + d;
  float pr = emb1[i];
  float t  = order1[r] * pr;
  float e2v = (acc - pr) - t;
  fstsum[i] = (fstsum[i] + pr) + e2v;
}

// ---------------- scores: one wave per row, exact numpy trees --------------
__global__ void __launch_bounds__(256) k_scores(const float* __restrict__ esum,
    const float* __restrict__ num_sum, const float* __restrict__ emb,
    uint32_t* __restrict__ m_arr, float* __restrict__ out_scores,
    uint32_t kna, uint32_t knb) {
#pragma clang fp contract(off)
  int r = blockIdx.x * 4 + (threadIdx.x >> 6);
  if (r >= NN) return;
  int lane = threadIdx.x & 63;
  size_t ib = (size_t)r * 64 + lane;
  float denom = num_sum[r] + 1e-8f;
  float t = esum[ib] / denom;
  float S1 = np_tree64(t * t);
  float nn = fmaxf(sqrtf(S1), 1e-12f);
  t = t / nn;
  float e = emb[ib];
  float S2 = np_tree64(e * e);
  float mn = fmaxf(sqrtf(S2), 1e-12f);
  float s = np_tree64(t * (e / mn));
  if (lane == 0) {
    float u  = u01_from_key(kna, knb, (uint32_t)r);
    float l1 = (float)log((double)u);
    float l2 = (float)log((double)(-l1));
    s = s + (-l2);
    uint32_t bb = __float_as_uint(s);
    m_arr[r] = bb ^ (uint32_t)(((int32_t)bb >> 31) | (int32_t)0x80000000);
    out_scores[r] = s;
  }
}

// ---------------- grid-parallel exact top-1024 ----------------
__global__ void __launch_bounds__(1024) k_h16(const uint32_t* __restrict__ m_arr,
                                              uint32_t* __restrict__ hist16) {
  int i = blockIdx.x * 1024 + threadIdx.x;
  if (i < NN) atomicAdd(&hist16[m_arr[i] >> 16], 1u);
}

__global__ void __launch_bounds__(1024) k_sel16(const uint32_t* __restrict__ hist16,
                                                uint32_t* __restrict__ selthr) {
  __shared__ uint32_t part[1024];
  int t = threadIdx.x;
  uint32_t s = 0;
  for (int j = 0; j < 64; j++) s += hist16[t * 64 + j];
  part[t] = s;
  __syncthreads();
  if (t == 0) {
    uint32_t acc = 0;
    int c = 1023;
    for (; c >= 0; c--) {
      if (acc + part[c] >= (uint32_t)NCAND) break;
      acc += part[c];
    }
    uint32_t thr = 0;
    if (c >= 0) {
      int b = c * 64 + 63;
      for (; b >= c * 64; b--) { acc += hist16[b]; if (acc >= (uint32_t)NCAND) break; }
      thr = (uint32_t)b << 16;
    }
    selthr[0] = thr;
  }
}

__global__ void __launch_bounds__(256) k_collect(const uint32_t* __restrict__ m_arr,
    const uint32_t* __restrict__ selthr, unsigned long long* __restrict__ cbuf,
    uint32_t* __restrict__ ccnt) {
  int i = blockIdx.x * blockDim.x + threadIdx.x;
  int stride = gridDim.x * blockDim.x;
  uint32_t thr = selthr[0];
  for (; i < NN; i += stride) {
    uint32_t m = m_arr[i];
    if (m >= thr) {
      uint32_t pos = atomicAdd(ccnt, 1u);
      if (pos < 4096u)
        cbuf[pos] = ((unsigned long long)m << 32) | (uint32_t)(~(uint32_t)i);
    }
  }
}

__global__ void __launch_bounds__(1024) k_sortemit(
    const unsigned long long* __restrict__ gcbuf, const uint32_t* __restrict__ ccnt,
    float* __restrict__ out) {
  __shared__ unsigned long long cbuf[4096];
  int tid = threadIdx.x;
  uint32_t n = *ccnt; if (n > 4096u) n = 4096u;
  for (int i = tid; i < 4096; i += 1024) cbuf[i] = (i < (int)n) ? gcbuf[i] : 0ULL;
  __syncthreads();
  for (int k = 2; k <= 4096; k <<= 1) {
    for (int j = k >> 1; j > 0; j >>= 1) {
      for (int i = tid; i < 4096; i += 1024) {
        int ixj = i ^ j;
        if (ixj > i) {
          bool up = ((i & k) == 0);
          unsigned long long a = cbuf[i], b = cbuf[ixj];
          if ((a > b) == up) { cbuf[i] = b; cbuf[ixj] = a; }
        }
      }
      __syncthreads();
    }
  }
  for (int j = tid; j < NCAND; j += 1024) {
    unsigned long long key = cbuf[4095 - j];
    uint32_t idx = ~(uint32_t)(key & 0xFFFFFFFFull);
    out[j] = (float)idx;
  }
}

// ---------------- launcher ----------------
extern "C" void kernel_launch(void* const* d_in, const int* in_sizes, int n_in,
                              void* d_out, int out_size, void* d_ws, size_t ws_size,
                              hipStream_t stream) {
  (void)in_sizes; (void)n_in; (void)out_size; (void)ws_size;
  const int*   rows = (const int*)d_in[0];
  const int*   cols = (const int*)d_in[1];
  const float* vals = (const float*)d_in[2];
  const float* emb  = (const float*)d_in[3];
  float* out = (float*)d_out;   // f32: scores[NN] then candidates[1024]

  char* w = (char*)d_ws;
  auto alloc = [&](size_t bytes) -> void* {
    void* p = (void*)w; w += (bytes + 255) & ~(size_t)255; return p;
  };
  uint32_t* bcur    = (uint32_t*)alloc((size_t)NB * 4);
  uint32_t* bbufE   = (uint32_t*)alloc((size_t)NB * CAP * 4);
  uint32_t* bbufC   = (uint32_t*)alloc((size_t)NB * CAP * 4);
  float*    bbufV   = (float*)   alloc((size_t)NB * CAP * 4);
  uint32_t* total   = (uint32_t*)alloc((size_t)NN * 4);
  uint32_t* totalA  = (uint32_t*)alloc((size_t)NN * 4);
  uint32_t* totalB  = (uint32_t*)alloc((size_t)NN * 4);
  uint32_t* rstart  = (uint32_t*)alloc((size_t)(NN + 1) * 4);
  uint32_t* rstartA = (uint32_t*)alloc((size_t)(NN + 1) * 4);
  uint32_t* rstartB = (uint32_t*)alloc((size_t)(NN + 1) * 4);
  uint32_t* bsum    = (uint32_t*)alloc((size_t)(3 * SCAN_BLOCKS) * 4);
  uint32_t* scol    = (uint32_t*)alloc((size_t)NE * 4);
  float*    v0s     = (float*)   alloc((size_t)NE * 4);
  uint32_t* scolA   = (uint32_t*)alloc((size_t)NA_CAP * 4);
  float*    vAa     = (float*)   alloc((size_t)NA_CAP * 4);
  uint32_t* scolB   = (uint32_t*)alloc((size_t)NB_CAP * 4);
  float*    vBa     = (float*)   alloc((size_t)NB_CAP * 4);
  float*    order0  = (float*)   alloc((size_t)NN * 4);
  float*    order1  = (float*)   alloc((size_t)NN * 4);
  float*    num0    = (float*)   alloc((size_t)NN * 4);
  float*    num_sum = (float*)   alloc((size_t)NN * 4);
  float*    fst     = (float*)   alloc((size_t)NN * 64 * 4);
  float*    emb1    = (float*)   alloc((size_t)NN * 64 * 4);
  uint32_t* m_arr   = (uint32_t*)alloc((size_t)NN * 4);
  uint32_t* hist16  = (uint32_t*)alloc((size_t)HBINS * 4);
  uint32_t* selthr  = (uint32_t*)alloc(4);
  uint32_t* gccnt   = (uint32_t*)alloc(4);
  unsigned long long* gcbuf = (unsigned long long*)alloc(4096 * 8);

  // host-side threefry key chain (data-independent)
  uint32_t K1a,K1b, kd0a,kd0b, K2a,K2b, kd1a,kd1b, kna,knb;
  tf2x32(0u, 42u, 0u, 0u, K1a, K1b);
  tf2x32(0u, 42u, 0u, 1u, kd0a, kd0b);
  tf2x32(K1a, K1b, 0u, 0u, K2a, K2b);
  tf2x32(K1a, K1b, 0u, 1u, kd1a, kd1b);
  tf2x32(K2a, K2b, 0u, 1u, kna, knb);

  hipMemsetAsync(bcur, 0, (size_t)NB * 4, stream);
  hipMemsetAsync(hist16, 0, (size_t)HBINS * 4, stream);
  hipMemsetAsync(gccnt, 0, 4, stream);

  const int TPB = 256;
  k_bucketA<<<(NE + TILE - 1) / TILE, TPB, 0, stream>>>(rows, cols, vals, bcur,
      bbufE, bbufC, bbufV, kd0a, kd0b, kd1a, kd1b);
  k_cnt<<<NB, TPB, 0, stream>>>(bcur, bbufE, total, totalA, totalB);
  dim3 sgrid(SCAN_BLOCKS, 3);
  k_scan1<<<sgrid, 1024, 0, stream>>>(total, totalA, totalB, rstart, rstartA, rstartB, bsum);
  k_scan2<<<1, 64, 0, stream>>>(bsum);
  k_scan3<<<sgrid, 1024, 0, stream>>>(rstart, rstartA, rstartB, bsum);
  k_buildB<<<NB, TPB, 0, stream>>>(bbufE, bbufC, bbufV, rstart, rstartA, rstartB,
      scol, v0s, scolA, vAa, scolB, vBa, order0, order1);
  k_fst<<<(NN + 3) / 4, TPB, 0, stream>>>(rstart, scol, v0s, emb, fst);
  k_numA<<<(NN + TPB - 1) / TPB, TPB, 0, stream>>>(rstartA, scolA, vAa, order0, num0);
  k_emb1<<<(NN + 3) / 4, TPB, 0, stream>>>(rstartA, scolA, vAa, fst, order0, emb1);
  k_numB<<<(NN + TPB - 1) / TPB, TPB, 0, stream>>>(rstartB, scolB, vBa, num0, order0, order1, num_sum);
  k_emb2<<<(NN + 3) / 4, TPB, 0, stream>>>(rstartB, scolB, vBa, emb1, order1, fst);
  k_scores<<<(NN + 3) / 4, TPB, 0, stream>>>(fst, num_sum, emb, m_arr, out, kna, knb);
  k_h16<<<(NN + 1023) / 1024, 1024, 0, stream>>>(m_arr, hist16);
  k_sel16<<<1, 1024, 0, stream>>>(hist16, selthr);
  k_collect<<<64, TPB, 0, stream>>>(m_arr, selthr, gcbuf, gccnt);
  k_sortemit<<<1, 1024, 0, stream>>>(gcbuf, gccnt, out + NN);
}